// Round 2
// baseline (1433.607 us; speedup 1.0000x reference)
//
#include <hip/hip_runtime.h>

#define NN 100000
#define NEG_SLOPE 0.2f
#define FOUT 32

// order-preserving float->uint mapping for atomicMax on floats
__device__ __forceinline__ unsigned ordf(float f) {
    unsigned u = __float_as_uint(f);
    return (u & 0x80000000u) ? ~u : (u | 0x80000000u);
}
__device__ __forceinline__ float unordf(unsigned u) {
    return (u & 0x80000000u) ? __uint_as_float(u & 0x7FFFFFFFu) : __uint_as_float(~u);
}

// h = X @ W  (+ optional bias), optional per-node attention dots a_src/a_dst
template <bool ATT, bool ADD_BIAS>
__global__ void transform_kernel(const float* __restrict__ X, const float* __restrict__ W,
                                 const float* __restrict__ att_s, const float* __restrict__ att_d,
                                 const float* __restrict__ bias,
                                 float* __restrict__ H, float* __restrict__ a_src,
                                 float* __restrict__ a_dst, int N, int Fin) {
    __shared__ float Wl[128 * FOUT];   // max Fin=128
    __shared__ float Xl[8 * 128];
    const int t = threadIdx.x;
    for (int i = t; i < Fin * FOUT; i += 256) Wl[i] = W[i];
    const int nodeBase = blockIdx.x * 8;
    for (int i = t; i < 8 * Fin; i += 256) {
        int r = i / Fin, c = i - r * Fin;
        int n = nodeBase + r;
        Xl[i] = (n < N) ? X[(long)n * Fin + c] : 0.f;
    }
    __syncthreads();
    const int ln = t >> 5;   // local node 0..7
    const int j  = t & 31;   // output feature
    const int n  = nodeBase + ln;
    float acc = 0.f;
    for (int k = 0; k < Fin; ++k)
        acc = fmaf(Xl[ln * Fin + k], Wl[k * FOUT + j], acc);
    if (ADD_BIAS) acc += bias[j];
    if (n < N) H[(long)n * FOUT + j] = acc;
    if (ATT) {
        float vs = acc * att_s[j];
        float vd = acc * att_d[j];
        #pragma unroll
        for (int m = 16; m >= 1; m >>= 1) {
            vs += __shfl_xor(vs, m, 32);
            vd += __shfl_xor(vd, m, 32);
        }
        if (j == 0 && n < N) { a_src[n] = vs; a_dst[n] = vd; }
    }
}

__device__ __forceinline__ void edge_sd(int i, int E, const int* __restrict__ src,
                                        const int* __restrict__ dst, int& s, int& d) {
    if (i < E) { s = src[i]; d = dst[i]; }
    else       { s = d = i - E; }   // self loop
}

__global__ void edge_max_kernel(const int* __restrict__ src, const int* __restrict__ dst,
                                const float* __restrict__ a_src, const float* __restrict__ a_dst,
                                unsigned* __restrict__ m, int E, int ET) {
    int i = blockIdx.x * blockDim.x + threadIdx.x;
    if (i >= ET) return;
    int s, d; edge_sd(i, E, src, dst, s, d);
    float e = a_src[s] + a_dst[d];
    e = e > 0.f ? e : NEG_SLOPE * e;
    atomicMax(m + d, ordf(e));
}

__global__ void edge_denom_kernel(const int* __restrict__ src, const int* __restrict__ dst,
                                  const float* __restrict__ a_src, const float* __restrict__ a_dst,
                                  const unsigned* __restrict__ m, float* __restrict__ denom,
                                  int E, int ET) {
    int i = blockIdx.x * blockDim.x + threadIdx.x;
    if (i >= ET) return;
    int s, d; edge_sd(i, E, src, dst, s, d);
    float e = a_src[s] + a_dst[d];
    e = e > 0.f ? e : NEG_SLOPE * e;
    atomicAdd(denom + d, __expf(e - unordf(m[d])));
}

// one lane per (edge, feature): accum[dst][j] += alpha * h[src][j],
// alpha = exp(e-m)/denom  (denom fully folded here, NOT in finalize)
__global__ void edge_accum_kernel(const int* __restrict__ src, const int* __restrict__ dst,
                                  const float* __restrict__ a_src, const float* __restrict__ a_dst,
                                  const unsigned* __restrict__ m, const float* __restrict__ denom,
                                  const float* __restrict__ H, float* __restrict__ accum,
                                  int E, int ET) {
    long tid = (long)blockIdx.x * blockDim.x + threadIdx.x;
    if (tid >= (long)ET * FOUT) return;
    int i = (int)(tid >> 5);
    int j = (int)(tid & 31);
    int s, d; edge_sd(i, E, src, dst, s, d);
    float e = a_src[s] + a_dst[d];
    e = e > 0.f ? e : NEG_SLOPE * e;
    float w = __expf(e - unordf(m[d])) / (denom[d] + 1e-16f);
    atomicAdd(accum + (long)d * FOUT + j, w * H[(long)s * FOUT + j]);
}

// in place: accum = relu(accum + bias)   (alpha already normalized)
__global__ void finalize_kernel(float* __restrict__ accum, const float* __restrict__ bias,
                                int N) {
    int tid = blockIdx.x * blockDim.x + threadIdx.x;
    if (tid >= N * FOUT) return;
    int j = tid & 31;
    accum[tid] = fmaxf(accum[tid] + bias[j], 0.f);
}

extern "C" void kernel_launch(void* const* d_in, const int* in_sizes, int n_in,
                              void* d_out, int out_size, void* d_ws, size_t ws_size,
                              hipStream_t stream) {
    const float* x   = (const float*)d_in[0];
    const int*   ei  = (const int*)d_in[1];
    const float* W1  = (const float*)d_in[2];
    const float* as1 = (const float*)d_in[3];
    const float* ad1 = (const float*)d_in[4];
    const float* b1  = (const float*)d_in[5];
    const float* W2  = (const float*)d_in[6];
    const float* as2 = (const float*)d_in[7];
    const float* ad2 = (const float*)d_in[8];
    const float* b2  = (const float*)d_in[9];
    const float* Wr  = (const float*)d_in[10];
    const float* br  = (const float*)d_in[11];
    float* out = (float*)d_out;

    const int E  = in_sizes[1] / 2;
    const int*  src = ei;
    const int*  dst = ei + E;
    const int ET = E + NN;

    const size_t NF = (size_t)NN * FOUT;
    // workspace: accum(NF) | H(NF) | m(NN) | den(NN) | asrc(NN) | adst(NN)
    float*    accum = (float*)d_ws;
    float*    H     = accum + NF;
    unsigned* m     = (unsigned*)(H + NF);
    float*    den   = (float*)(m + NN);
    float*    asrc  = den + NN;
    float*    adst  = asrc + NN;

    dim3 blk(256);
    const int nb = (NN + 7) / 8;                            // transform blocks (8 nodes/block)
    const int eb = (ET + 255) / 256;                        // per-edge blocks
    const int ab = (int)(((long)ET * FOUT + 255) / 256);    // per-(edge,feature) blocks
    const int fb = (NN * FOUT + 255) / 256;

    // ---- layer 1 ----
    hipMemsetAsync(accum, 0, NF * sizeof(float), stream);
    hipMemsetAsync(m, 0, 2 * NN * sizeof(float), stream);   // m + den
    transform_kernel<true, false><<<nb, blk, 0, stream>>>(x, W1, as1, ad1, nullptr,
                                                          H, asrc, adst, NN, 128);
    edge_max_kernel<<<eb, blk, 0, stream>>>(src, dst, asrc, adst, m, E, ET);
    edge_denom_kernel<<<eb, blk, 0, stream>>>(src, dst, asrc, adst, m, den, E, ET);
    edge_accum_kernel<<<ab, blk, 0, stream>>>(src, dst, asrc, adst, m, den, H, accum, E, ET);
    finalize_kernel<<<fb, blk, 0, stream>>>(accum, b1, NN);

    // ---- layer 2 ---- (input = accum, transformed into H; then accum reused)
    transform_kernel<true, false><<<nb, blk, 0, stream>>>(accum, W2, as2, ad2, nullptr,
                                                          H, asrc, adst, NN, 32);
    hipMemsetAsync(accum, 0, NF * sizeof(float), stream);
    hipMemsetAsync(m, 0, 2 * NN * sizeof(float), stream);   // m + den
    edge_max_kernel<<<eb, blk, 0, stream>>>(src, dst, asrc, adst, m, E, ET);
    edge_denom_kernel<<<eb, blk, 0, stream>>>(src, dst, asrc, adst, m, den, E, ET);
    edge_accum_kernel<<<ab, blk, 0, stream>>>(src, dst, asrc, adst, m, den, H, accum, E, ET);
    finalize_kernel<<<fb, blk, 0, stream>>>(accum, b2, NN);

    // ---- readout ----  out = h2 @ Wr + br
    transform_kernel<false, true><<<nb, blk, 0, stream>>>(accum, Wr, nullptr, nullptr, br,
                                                          out, nullptr, nullptr, NN, 32);
}

// Round 3
// 801.481 us; speedup vs baseline: 1.7887x; 1.7887x over previous
//
#include <hip/hip_runtime.h>

#define NN 100000
#define NEG_SLOPE 0.2f
#define FOUT 32

// ---------------- shared: node transform ----------------
// h = X @ W  (+ optional bias), optional per-node attention dots a_src/a_dst
template <bool ATT, bool ADD_BIAS>
__global__ void transform_kernel(const float* __restrict__ X, const float* __restrict__ W,
                                 const float* __restrict__ att_s, const float* __restrict__ att_d,
                                 const float* __restrict__ bias,
                                 float* __restrict__ H, float* __restrict__ a_src,
                                 float* __restrict__ a_dst, int N, int Fin) {
    __shared__ float Wl[128 * FOUT];
    __shared__ float Xl[8 * 128];
    const int t = threadIdx.x;
    for (int i = t; i < Fin * FOUT; i += 256) Wl[i] = W[i];
    const int nodeBase = blockIdx.x * 8;
    for (int i = t; i < 8 * Fin; i += 256) {
        int r = i / Fin, c = i - r * Fin;
        int n = nodeBase + r;
        Xl[i] = (n < N) ? X[(long)n * Fin + c] : 0.f;
    }
    __syncthreads();
    const int ln = t >> 5;
    const int j  = t & 31;
    const int n  = nodeBase + ln;
    float acc = 0.f;
    for (int k = 0; k < Fin; ++k)
        acc = fmaf(Xl[ln * Fin + k], Wl[k * FOUT + j], acc);
    if (ADD_BIAS) acc += bias[j];
    if (n < N) H[(long)n * FOUT + j] = acc;
    if (ATT) {
        float vs = acc * att_s[j];
        float vd = acc * att_d[j];
        #pragma unroll
        for (int m = 16; m >= 1; m >>= 1) {
            vs += __shfl_xor(vs, m, 32);
            vd += __shfl_xor(vd, m, 32);
        }
        if (j == 0 && n < N) { a_src[n] = vs; a_dst[n] = vd; }
    }
}

// ---------------- CSR build ----------------
__global__ void init_one_kernel(int* __restrict__ cnt, int n) {
    int i = blockIdx.x * blockDim.x + threadIdx.x;
    if (i < n) cnt[i] = 1;   // self loop
}

__global__ void hist_kernel(const int* __restrict__ dst, int E, int* __restrict__ cnt) {
    int i = blockIdx.x * blockDim.x + threadIdx.x;
    if (i < E) atomicAdd(&cnt[dst[i]], 1);
}

template <int BS>
__global__ void scan_blocks_kernel(const int* __restrict__ in, int n,
                                   int* __restrict__ out, int* __restrict__ bsums) {
    int g = blockIdx.x * BS + threadIdx.x;
    int v = (g < n) ? in[g] : 0;
    int lane = threadIdx.x & 63;
    int w = threadIdx.x >> 6;
    int x = v;
    #pragma unroll
    for (int o = 1; o < 64; o <<= 1) {
        int y = __shfl_up(x, o, 64);
        if (lane >= o) x += y;
    }
    __shared__ int ws[BS / 64];
    if (lane == 63) ws[w] = x;
    __syncthreads();
    if (threadIdx.x == 0) {
        int a = 0;
        for (int k = 0; k < BS / 64; ++k) { int tv = ws[k]; ws[k] = a; a += tv; }
        if (bsums) bsums[blockIdx.x] = a;
    }
    __syncthreads();
    int ex = x - v + ws[w];   // exclusive scan value
    if (g < n) out[g] = ex;
}

__global__ void add_offsets_kernel(int* __restrict__ out, const int* __restrict__ bsums, int n) {
    int g = blockIdx.x * 256 + threadIdx.x;
    if (g < n) out[g] += bsums[blockIdx.x];
}

__global__ void scatter_kernel(const int* __restrict__ src, const int* __restrict__ dst,
                               int E, int ET, const int* __restrict__ ptr,
                               int* __restrict__ fill, int* __restrict__ ssrc) {
    int i = blockIdx.x * blockDim.x + threadIdx.x;
    if (i >= ET) return;
    int s, d;
    if (i < E) { s = src[i]; d = dst[i]; }
    else       { s = d = i - E; }
    int pos = ptr[d] + atomicAdd(&fill[d], 1);
    ssrc[pos] = s;
}

// ---------------- fused per-node GAT aggregation (CSR gather) ----------------
// one 64-lane wave per destination node: max -> denom -> accumulate, bias+relu folded
__global__ void gat_edge_csr_kernel(const int* __restrict__ ptr, const int* __restrict__ ssrc,
                                    const float* __restrict__ asrc, const float* __restrict__ adst,
                                    const float* __restrict__ H, const float* __restrict__ bias,
                                    float* __restrict__ out, int relu, int ET) {
    int wid  = (int)(((long)blockIdx.x * blockDim.x + threadIdx.x) >> 6);
    int lane = threadIdx.x & 63;
    if (wid >= NN) return;
    int beg = ptr[wid];
    int end = (wid == NN - 1) ? ET : ptr[wid + 1];
    int deg = end - beg;
    float ad = adst[wid];

    // pass A: segment max
    float mx = -1e30f;
    for (int k = lane; k < deg; k += 64) {
        int s = ssrc[beg + k];
        float e = asrc[s] + ad;
        e = e > 0.f ? e : NEG_SLOPE * e;
        mx = fmaxf(mx, e);
    }
    #pragma unroll
    for (int o = 32; o >= 1; o >>= 1) mx = fmaxf(mx, __shfl_xor(mx, o, 64));

    // pass B: denom
    float sm = 0.f;
    for (int k = lane; k < deg; k += 64) {
        int s = ssrc[beg + k];
        float e = asrc[s] + ad;
        e = e > 0.f ? e : NEG_SLOPE * e;
        sm += __expf(e - mx);
    }
    #pragma unroll
    for (int o = 32; o >= 1; o >>= 1) sm += __shfl_xor(sm, o, 64);
    float inv = 1.f / (sm + 1e-16f);

    // pass C: weighted accumulate; half-waves take alternate edges, lane&31 = feature
    int half = lane >> 5, j = lane & 31;
    float acc = 0.f;
    for (int k = half; k < deg; k += 2) {
        int s = ssrc[beg + k];              // uniform within half-wave -> broadcast
        float e = asrc[s] + ad;
        e = e > 0.f ? e : NEG_SLOPE * e;
        float w = __expf(e - mx) * inv;
        acc = fmaf(w, H[(long)s * FOUT + j], acc);
    }
    acc += __shfl_xor(acc, 32, 64);
    if (lane < 32) {
        float v = acc + bias[j];
        if (relu) v = fmaxf(v, 0.f);
        out[(long)wid * FOUT + j] = v;
    }
}

// ---------------- fallback (round-2 proven atomic path) ----------------
__device__ __forceinline__ unsigned ordf(float f) {
    unsigned u = __float_as_uint(f);
    return (u & 0x80000000u) ? ~u : (u | 0x80000000u);
}
__device__ __forceinline__ float unordf(unsigned u) {
    return (u & 0x80000000u) ? __uint_as_float(u & 0x7FFFFFFFu) : __uint_as_float(~u);
}
__device__ __forceinline__ void edge_sd(int i, int E, const int* __restrict__ src,
                                        const int* __restrict__ dst, int& s, int& d) {
    if (i < E) { s = src[i]; d = dst[i]; }
    else       { s = d = i - E; }
}
__global__ void edge_max_kernel(const int* __restrict__ src, const int* __restrict__ dst,
                                const float* __restrict__ a_src, const float* __restrict__ a_dst,
                                unsigned* __restrict__ m, int E, int ET) {
    int i = blockIdx.x * blockDim.x + threadIdx.x;
    if (i >= ET) return;
    int s, d; edge_sd(i, E, src, dst, s, d);
    float e = a_src[s] + a_dst[d];
    e = e > 0.f ? e : NEG_SLOPE * e;
    atomicMax(m + d, ordf(e));
}
__global__ void edge_denom_kernel(const int* __restrict__ src, const int* __restrict__ dst,
                                  const float* __restrict__ a_src, const float* __restrict__ a_dst,
                                  const unsigned* __restrict__ m, float* __restrict__ denom,
                                  int E, int ET) {
    int i = blockIdx.x * blockDim.x + threadIdx.x;
    if (i >= ET) return;
    int s, d; edge_sd(i, E, src, dst, s, d);
    float e = a_src[s] + a_dst[d];
    e = e > 0.f ? e : NEG_SLOPE * e;
    atomicAdd(denom + d, __expf(e - unordf(m[d])));
}
__global__ void edge_accum_kernel(const int* __restrict__ src, const int* __restrict__ dst,
                                  const float* __restrict__ a_src, const float* __restrict__ a_dst,
                                  const unsigned* __restrict__ m, const float* __restrict__ denom,
                                  const float* __restrict__ H, float* __restrict__ accum,
                                  int E, int ET) {
    long tid = (long)blockIdx.x * blockDim.x + threadIdx.x;
    if (tid >= (long)ET * FOUT) return;
    int i = (int)(tid >> 5);
    int j = (int)(tid & 31);
    int s, d; edge_sd(i, E, src, dst, s, d);
    float e = a_src[s] + a_dst[d];
    e = e > 0.f ? e : NEG_SLOPE * e;
    float w = __expf(e - unordf(m[d])) / (denom[d] + 1e-16f);
    atomicAdd(accum + (long)d * FOUT + j, w * H[(long)s * FOUT + j]);
}
__global__ void finalize_kernel(float* __restrict__ accum, const float* __restrict__ bias, int N) {
    int tid = blockIdx.x * blockDim.x + threadIdx.x;
    if (tid >= N * FOUT) return;
    int j = tid & 31;
    accum[tid] = fmaxf(accum[tid] + bias[j], 0.f);
}

extern "C" void kernel_launch(void* const* d_in, const int* in_sizes, int n_in,
                              void* d_out, int out_size, void* d_ws, size_t ws_size,
                              hipStream_t stream) {
    const float* x   = (const float*)d_in[0];
    const int*   ei  = (const int*)d_in[1];
    const float* W1  = (const float*)d_in[2];
    const float* as1 = (const float*)d_in[3];
    const float* ad1 = (const float*)d_in[4];
    const float* b1  = (const float*)d_in[5];
    const float* W2  = (const float*)d_in[6];
    const float* as2 = (const float*)d_in[7];
    const float* ad2 = (const float*)d_in[8];
    const float* b2  = (const float*)d_in[9];
    const float* Wr  = (const float*)d_in[10];
    const float* br  = (const float*)d_in[11];
    float* out = (float*)d_out;

    const int E  = in_sizes[1] / 2;
    const int*  src = ei;
    const int*  dst = ei + E;
    const int ET = E + NN;

    const size_t NF = (size_t)NN * FOUT;
    // layout: A(NF) | H(NF) | asrc(NN) | adst(NN) | ptr(NN) | cntfill(NN) | bsum(512) | ssrc(ET)
    float* A     = (float*)d_ws;
    float* H     = A + NF;
    float* asrc  = H + NF;
    float* adst  = asrc + NN;
    int*   ptr   = (int*)(adst + NN);
    int*   cfill = ptr + NN;
    int*   bsum  = cfill + NN;
    int*   ssrc  = bsum + 512;
    const size_t need = (2 * NF + 4 * (size_t)NN + 512 + (size_t)ET) * 4;

    dim3 blk(256);
    const int nb = (NN + 7) / 8;
    const int fb = (NN * FOUT + 255) / 256;

    if (ws_size >= need) {
        // ================= CSR gather path =================
        const int nb1 = (NN + 255) / 256;         // scan level-1 blocks (391)
        const int ebE = (E + 255) / 256;
        const int ebT = (ET + 255) / 256;
        const int wb  = (NN * 64 + 255) / 256;    // 1 wave per node

        // build CSR
        init_one_kernel<<<nb1, blk, 0, stream>>>(cfill, NN);
        hist_kernel<<<ebE, blk, 0, stream>>>(dst, E, cfill);
        scan_blocks_kernel<256><<<nb1, blk, 0, stream>>>(cfill, NN, ptr, bsum);
        scan_blocks_kernel<512><<<1, 512, 0, stream>>>(bsum, nb1, bsum, nullptr);
        add_offsets_kernel<<<nb1, blk, 0, stream>>>(ptr, bsum, NN);
        hipMemsetAsync(cfill, 0, NN * sizeof(int), stream);
        scatter_kernel<<<ebT, blk, 0, stream>>>(src, dst, E, ET, ptr, cfill, ssrc);

        // layer 1
        transform_kernel<true, false><<<nb, blk, 0, stream>>>(x, W1, as1, ad1, nullptr,
                                                              H, asrc, adst, NN, 128);
        gat_edge_csr_kernel<<<wb, blk, 0, stream>>>(ptr, ssrc, asrc, adst, H, b1, A, 1, ET);
        // layer 2
        transform_kernel<true, false><<<nb, blk, 0, stream>>>(A, W2, as2, ad2, nullptr,
                                                              H, asrc, adst, NN, 32);
        gat_edge_csr_kernel<<<wb, blk, 0, stream>>>(ptr, ssrc, asrc, adst, H, b2, A, 1, ET);
        // readout
        transform_kernel<false, true><<<nb, blk, 0, stream>>>(A, Wr, nullptr, nullptr, br,
                                                              out, nullptr, nullptr, NN, 32);
    } else {
        // ================= fallback: round-2 atomic path =================
        unsigned* m   = (unsigned*)ptr;
        float*    den = (float*)cfill;
        const int eb = (ET + 255) / 256;
        const int ab = (int)(((long)ET * FOUT + 255) / 256);

        hipMemsetAsync(A, 0, NF * sizeof(float), stream);
        hipMemsetAsync(m, 0, NN * sizeof(int), stream);
        hipMemsetAsync(den, 0, NN * sizeof(float), stream);
        transform_kernel<true, false><<<nb, blk, 0, stream>>>(x, W1, as1, ad1, nullptr,
                                                              H, asrc, adst, NN, 128);
        edge_max_kernel<<<eb, blk, 0, stream>>>(src, dst, asrc, adst, m, E, ET);
        edge_denom_kernel<<<eb, blk, 0, stream>>>(src, dst, asrc, adst, m, den, E, ET);
        edge_accum_kernel<<<ab, blk, 0, stream>>>(src, dst, asrc, adst, m, den, H, A, E, ET);
        finalize_kernel<<<fb, blk, 0, stream>>>(A, b1, NN);

        transform_kernel<true, false><<<nb, blk, 0, stream>>>(A, W2, as2, ad2, nullptr,
                                                              H, asrc, adst, NN, 32);
        hipMemsetAsync(A, 0, NF * sizeof(float), stream);
        hipMemsetAsync(m, 0, NN * sizeof(int), stream);
        hipMemsetAsync(den, 0, NN * sizeof(float), stream);
        edge_max_kernel<<<eb, blk, 0, stream>>>(src, dst, asrc, adst, m, E, ET);
        edge_denom_kernel<<<eb, blk, 0, stream>>>(src, dst, asrc, adst, m, den, E, ET);
        edge_accum_kernel<<<ab, blk, 0, stream>>>(src, dst, asrc, adst, m, den, H, A, E, ET);
        finalize_kernel<<<fb, blk, 0, stream>>>(A, b2, NN);

        transform_kernel<false, true><<<nb, blk, 0, stream>>>(A, Wr, nullptr, nullptr, br,
                                                              out, nullptr, nullptr, NN, 32);
    }
}

// Round 4
// 675.842 us; speedup vs baseline: 2.1212x; 1.1859x over previous
//
#include <hip/hip_runtime.h>

#define NN 100000
#define NEG_SLOPE 0.2f
#define FOUT 32
#define CAP 128

__device__ __forceinline__ float lrelu(float e) { return e > 0.f ? e : NEG_SLOPE * e; }

// ---------------- node transform: h = X @ W (+bias), optional attention dots ----------------
template <bool ATT, bool ADD_BIAS>
__global__ void transform_kernel(const float* __restrict__ X, const float* __restrict__ W,
                                 const float* __restrict__ att_s, const float* __restrict__ att_d,
                                 const float* __restrict__ bias,
                                 float* __restrict__ H, float* __restrict__ a_src,
                                 float* __restrict__ a_dst, int N, int Fin) {
    __shared__ float Wl[128 * FOUT];
    __shared__ float Xl[8 * 128];
    const int t = threadIdx.x;
    const int nodeBase = blockIdx.x * 8;
    const int vprW = Fin * FOUT / 4;
    for (int i = t; i < vprW; i += 256) ((float4*)Wl)[i] = ((const float4*)W)[i];
    const int vpr = Fin / 4;
    for (int i = t; i < 8 * vpr; i += 256) {
        int r = i / vpr, c = i - r * vpr;
        int n = nodeBase + r;
        ((float4*)Xl)[i] = (n < N) ? ((const float4*)X)[(size_t)n * vpr + c]
                                   : make_float4(0.f, 0.f, 0.f, 0.f);
    }
    __syncthreads();
    const int ln = t >> 5;
    const int j  = t & 31;
    const int n  = nodeBase + ln;
    float acc = 0.f;
    for (int k = 0; k < Fin; ++k)
        acc = fmaf(Xl[ln * Fin + k], Wl[k * FOUT + j], acc);
    if (ADD_BIAS) acc += bias[j];
    if (n < N) H[(size_t)n * FOUT + j] = acc;
    if (ATT) {
        float vs = acc * att_s[j];
        float vd = acc * att_d[j];
        #pragma unroll
        for (int m = 16; m >= 1; m >>= 1) {
            vs += __shfl_xor(vs, m, 32);
            vd += __shfl_xor(vd, m, 32);
        }
        if (j == 0 && n < N) { a_src[n] = vs; a_dst[n] = vd; }
    }
}

// ---------------- CSR build ----------------
__global__ void init_one_kernel(int* __restrict__ cnt, int n) {
    int i = blockIdx.x * blockDim.x + threadIdx.x;
    if (i < n) cnt[i] = 1;   // self loop
}

__global__ void hist_kernel(const int* __restrict__ dst, int E, int* __restrict__ cnt) {
    int i = blockIdx.x * blockDim.x + threadIdx.x;
    if (i < E) atomicAdd(&cnt[__builtin_nontemporal_load(dst + i)], 1);
}

template <int BS>
__global__ void scan_blocks_kernel(const int* __restrict__ in, int n,
                                   int* __restrict__ out, int* __restrict__ bsums) {
    int g = blockIdx.x * BS + threadIdx.x;
    int v = (g < n) ? in[g] : 0;
    int lane = threadIdx.x & 63;
    int w = threadIdx.x >> 6;
    int x = v;
    #pragma unroll
    for (int o = 1; o < 64; o <<= 1) {
        int y = __shfl_up(x, o, 64);
        if (lane >= o) x += y;
    }
    __shared__ int ws[BS / 64];
    if (lane == 63) ws[w] = x;
    __syncthreads();
    if (threadIdx.x == 0) {
        int a = 0;
        for (int k = 0; k < BS / 64; ++k) { int tv = ws[k]; ws[k] = a; a += tv; }
        if (bsums) bsums[blockIdx.x] = a;
    }
    __syncthreads();
    int ex = x - v + ws[w];
    if (g < n) out[g] = ex;
}

__global__ void add_offsets_kernel(int* __restrict__ out, const int* __restrict__ bsums, int n) {
    int g = blockIdx.x * 256 + threadIdx.x;
    if (g < n) out[g] += bsums[blockIdx.x];
}

__global__ void copy_kernel(const int* __restrict__ in, int* __restrict__ out, int n) {
    int i = blockIdx.x * blockDim.x + threadIdx.x;
    if (i < n) out[i] = in[i];
}

// cfill pre-initialized to ptr -> atomicAdd returns absolute position
__global__ void scatter_kernel(const int* __restrict__ src, const int* __restrict__ dst,
                               int E, int ET, int* __restrict__ cfill, int* __restrict__ ssrc) {
    int i = blockIdx.x * blockDim.x + threadIdx.x;
    if (i >= ET) return;
    int s, d;
    if (i < E) { s = __builtin_nontemporal_load(src + i); d = __builtin_nontemporal_load(dst + i); }
    else       { s = d = i - E; }
    int pos = atomicAdd(&cfill[d], 1);
    __builtin_nontemporal_store(s, ssrc + pos);
}

// ---------------- fused per-node GAT aggregation (CSR gather) ----------------
// one 64-lane wave per node; (s,e) LDS-cached; pass C: quarter-waves, float2 H loads.
// FUSE_OUT: epilogue computes relu(agg+bias) @ Wr + br -> out (readout fusion)
template <bool FUSE_OUT>
__global__ __launch_bounds__(256)
void gat_csr_kernel(const int* __restrict__ ptr, const int* __restrict__ ssrc,
                    const float* __restrict__ asrc, const float* __restrict__ adst,
                    const float* __restrict__ H, const float* __restrict__ bias,
                    const float* __restrict__ Wr, const float* __restrict__ br,
                    float* __restrict__ out, int ET) {
    __shared__ float Wl[32 * 32];
    __shared__ float ebuf[4][CAP];
    __shared__ int   sbuf[4][CAP];
    const int tid = threadIdx.x;
    if (FUSE_OUT) {
        for (int i = tid; i < 1024; i += 256) Wl[i] = Wr[i];
    }
    const int w = tid >> 6, lane = tid & 63;
    const int wid = blockIdx.x * 4 + w;          // grid = 25000 blocks -> wid < NN always
    const int beg = ptr[wid];
    const int end = (wid == NN - 1) ? ET : ptr[wid + 1];
    const int deg = end - beg;
    const int cap = min(deg, CAP);
    const float ad = adst[wid];

    // pass A: load edges once, cache (s,e) in LDS, track max
    float mx = -1e30f;
    for (int k = lane; k < cap; k += 64) {
        int s = ssrc[beg + k];
        float e = lrelu(asrc[s] + ad);
        sbuf[w][k] = s; ebuf[w][k] = e;
        mx = fmaxf(mx, e);
    }
    for (int k = cap + lane; k < deg; k += 64) {          // deg > CAP: rare fallback
        int s = ssrc[beg + k];
        mx = fmaxf(mx, lrelu(asrc[s] + ad));
    }
    #pragma unroll
    for (int o = 32; o; o >>= 1) mx = fmaxf(mx, __shfl_xor(mx, o, 64));

    __syncthreads();   // sbuf/ebuf (+Wl) visible

    // pass B: denom
    float sm = 0.f;
    for (int k = lane; k < cap; k += 64) sm += __expf(ebuf[w][k] - mx);
    for (int k = cap + lane; k < deg; k += 64) {
        int s = ssrc[beg + k];
        sm += __expf(lrelu(asrc[s] + ad) - mx);
    }
    #pragma unroll
    for (int o = 32; o; o >>= 1) sm += __shfl_xor(sm, o, 64);
    const float inv = 1.f / (sm + 1e-16f);

    // pass C: quarter q handles edges k === q (mod 4); lane t holds features (2t, 2t+1)
    const int q = lane >> 4, t = lane & 15;
    float ax0 = 0.f, ay0 = 0.f, ax1 = 0.f, ay1 = 0.f;
    int k = q;
    for (; k + 4 < deg; k += 8) {
        int s0; float e0;
        if (k < cap) { s0 = sbuf[w][k]; e0 = ebuf[w][k]; }
        else         { s0 = ssrc[beg + k]; e0 = lrelu(asrc[s0] + ad); }
        int k1 = k + 4; int s1; float e1;
        if (k1 < cap) { s1 = sbuf[w][k1]; e1 = ebuf[w][k1]; }
        else          { s1 = ssrc[beg + k1]; e1 = lrelu(asrc[s1] + ad); }
        float w0 = __expf(e0 - mx), w1 = __expf(e1 - mx);
        float2 h0 = *(const float2*)(H + (size_t)s0 * FOUT + 2 * t);
        float2 h1 = *(const float2*)(H + (size_t)s1 * FOUT + 2 * t);
        ax0 = fmaf(w0, h0.x, ax0); ay0 = fmaf(w0, h0.y, ay0);
        ax1 = fmaf(w1, h1.x, ax1); ay1 = fmaf(w1, h1.y, ay1);
    }
    for (; k < deg; k += 4) {
        int s; float e;
        if (k < cap) { s = sbuf[w][k]; e = ebuf[w][k]; }
        else         { s = ssrc[beg + k]; e = lrelu(asrc[s] + ad); }
        float w0 = __expf(e - mx);
        float2 h = *(const float2*)(H + (size_t)s * FOUT + 2 * t);
        ax0 = fmaf(w0, h.x, ax0); ay0 = fmaf(w0, h.y, ay0);
    }
    float ax = ax0 + ax1, ay = ay0 + ay1;
    ax += __shfl_xor(ax, 16, 64); ay += __shfl_xor(ay, 16, 64);
    ax += __shfl_xor(ax, 32, 64); ay += __shfl_xor(ay, 32, 64);

    if (!FUSE_OUT) {
        if (lane < 16) {
            float vx = fmaxf(ax * inv + bias[2 * t],     0.f);
            float vy = fmaxf(ay * inv + bias[2 * t + 1], 0.f);
            *(float2*)(out + (size_t)wid * FOUT + 2 * t) = make_float2(vx, vy);
        }
    } else {
        if (lane < 16) {
            ebuf[w][2 * t]     = fmaxf(ax * inv + bias[2 * t],     0.f);
            ebuf[w][2 * t + 1] = fmaxf(ay * inv + bias[2 * t + 1], 0.f);
        }
        __syncthreads();
        if (lane < 16) {
            float rx = br[2 * t], ry = br[2 * t + 1];
            #pragma unroll
            for (int j = 0; j < 32; ++j) {
                float hj = ebuf[w][j];
                rx = fmaf(hj, Wl[j * 32 + 2 * t],     rx);
                ry = fmaf(hj, Wl[j * 32 + 2 * t + 1], ry);
            }
            *(float2*)(out + (size_t)wid * FOUT + 2 * t) = make_float2(rx, ry);
        }
    }
}

// ---------------- fallback (round-2 proven atomic path) ----------------
__device__ __forceinline__ unsigned ordf(float f) {
    unsigned u = __float_as_uint(f);
    return (u & 0x80000000u) ? ~u : (u | 0x80000000u);
}
__device__ __forceinline__ float unordf(unsigned u) {
    return (u & 0x80000000u) ? __uint_as_float(u & 0x7FFFFFFFu) : __uint_as_float(~u);
}
__device__ __forceinline__ void edge_sd(int i, int E, const int* __restrict__ src,
                                        const int* __restrict__ dst, int& s, int& d) {
    if (i < E) { s = src[i]; d = dst[i]; }
    else       { s = d = i - E; }
}
__global__ void edge_max_kernel(const int* __restrict__ src, const int* __restrict__ dst,
                                const float* __restrict__ a_src, const float* __restrict__ a_dst,
                                unsigned* __restrict__ m, int E, int ET) {
    int i = blockIdx.x * blockDim.x + threadIdx.x;
    if (i >= ET) return;
    int s, d; edge_sd(i, E, src, dst, s, d);
    atomicMax(m + d, ordf(lrelu(a_src[s] + a_dst[d])));
}
__global__ void edge_denom_kernel(const int* __restrict__ src, const int* __restrict__ dst,
                                  const float* __restrict__ a_src, const float* __restrict__ a_dst,
                                  const unsigned* __restrict__ m, float* __restrict__ denom,
                                  int E, int ET) {
    int i = blockIdx.x * blockDim.x + threadIdx.x;
    if (i >= ET) return;
    int s, d; edge_sd(i, E, src, dst, s, d);
    atomicAdd(denom + d, __expf(lrelu(a_src[s] + a_dst[d]) - unordf(m[d])));
}
__global__ void edge_accum_kernel(const int* __restrict__ src, const int* __restrict__ dst,
                                  const float* __restrict__ a_src, const float* __restrict__ a_dst,
                                  const unsigned* __restrict__ m, const float* __restrict__ denom,
                                  const float* __restrict__ H, float* __restrict__ accum,
                                  int E, int ET) {
    long tid = (long)blockIdx.x * blockDim.x + threadIdx.x;
    if (tid >= (long)ET * FOUT) return;
    int i = (int)(tid >> 5);
    int j = (int)(tid & 31);
    int s, d; edge_sd(i, E, src, dst, s, d);
    float w = __expf(lrelu(a_src[s] + a_dst[d]) - unordf(m[d])) / (denom[d] + 1e-16f);
    atomicAdd(accum + (long)d * FOUT + j, w * H[(long)s * FOUT + j]);
}
__global__ void finalize_kernel(float* __restrict__ accum, const float* __restrict__ bias, int N) {
    int tid = blockIdx.x * blockDim.x + threadIdx.x;
    if (tid >= N * FOUT) return;
    int j = tid & 31;
    accum[tid] = fmaxf(accum[tid] + bias[j], 0.f);
}

extern "C" void kernel_launch(void* const* d_in, const int* in_sizes, int n_in,
                              void* d_out, int out_size, void* d_ws, size_t ws_size,
                              hipStream_t stream) {
    const float* x   = (const float*)d_in[0];
    const int*   ei  = (const int*)d_in[1];
    const float* W1  = (const float*)d_in[2];
    const float* as1 = (const float*)d_in[3];
    const float* ad1 = (const float*)d_in[4];
    const float* b1  = (const float*)d_in[5];
    const float* W2  = (const float*)d_in[6];
    const float* as2 = (const float*)d_in[7];
    const float* ad2 = (const float*)d_in[8];
    const float* b2  = (const float*)d_in[9];
    const float* Wr  = (const float*)d_in[10];
    const float* br  = (const float*)d_in[11];
    float* out = (float*)d_out;

    const int E  = in_sizes[1] / 2;
    const int*  src = ei;
    const int*  dst = ei + E;
    const int ET = E + NN;

    const size_t NF = (size_t)NN * FOUT;
    // layout: A(NF) | H(NF) | asrc(NN) | adst(NN) | ptr(NN) | cfill(NN) | bsum(512) | ssrc(ET)
    float* A     = (float*)d_ws;
    float* H     = A + NF;
    float* asrc  = H + NF;
    float* adst  = asrc + NN;
    int*   ptr   = (int*)(adst + NN);
    int*   cfill = ptr + NN;
    int*   bsum  = cfill + NN;
    int*   ssrc  = bsum + 512;
    const size_t need = (2 * NF + 4 * (size_t)NN + 512 + (size_t)ET) * 4;

    dim3 blk(256);
    const int nb = (NN + 7) / 8;
    const int fb = (NN * FOUT + 255) / 256;

    if (ws_size >= need) {
        // ================= CSR gather path =================
        const int nb1 = (NN + 255) / 256;         // 391
        const int ebE = (E + 255) / 256;
        const int ebT = (ET + 255) / 256;
        const int gb  = NN / 4;                   // 4 nodes (waves) per block -> 25000

        // build CSR (cfill ends as absolute fill cursor = ptr copy)
        init_one_kernel<<<nb1, blk, 0, stream>>>(cfill, NN);
        hist_kernel<<<ebE, blk, 0, stream>>>(dst, E, cfill);
        scan_blocks_kernel<256><<<nb1, blk, 0, stream>>>(cfill, NN, ptr, bsum);
        scan_blocks_kernel<512><<<1, 512, 0, stream>>>(bsum, nb1, bsum, nullptr);
        add_offsets_kernel<<<nb1, blk, 0, stream>>>(ptr, bsum, NN);
        copy_kernel<<<nb1, blk, 0, stream>>>(ptr, cfill, NN);
        scatter_kernel<<<ebT, blk, 0, stream>>>(src, dst, E, ET, cfill, ssrc);

        // layer 1
        transform_kernel<true, false><<<nb, blk, 0, stream>>>(x, W1, as1, ad1, nullptr,
                                                              H, asrc, adst, NN, 128);
        gat_csr_kernel<false><<<gb, blk, 0, stream>>>(ptr, ssrc, asrc, adst, H, b1,
                                                      nullptr, nullptr, A, ET);
        // layer 2 + fused readout
        transform_kernel<true, false><<<nb, blk, 0, stream>>>(A, W2, as2, ad2, nullptr,
                                                              H, asrc, adst, NN, 32);
        gat_csr_kernel<true><<<gb, blk, 0, stream>>>(ptr, ssrc, asrc, adst, H, b2,
                                                     Wr, br, out, ET);
    } else {
        // ================= fallback: atomic path =================
        unsigned* m   = (unsigned*)ptr;
        float*    den = (float*)cfill;
        const int eb = (ET + 255) / 256;
        const int ab = (int)(((long)ET * FOUT + 255) / 256);

        hipMemsetAsync(A, 0, NF * sizeof(float), stream);
        hipMemsetAsync(m, 0, NN * sizeof(int), stream);
        hipMemsetAsync(den, 0, NN * sizeof(float), stream);
        transform_kernel<true, false><<<nb, blk, 0, stream>>>(x, W1, as1, ad1, nullptr,
                                                              H, asrc, adst, NN, 128);
        edge_max_kernel<<<eb, blk, 0, stream>>>(src, dst, asrc, adst, m, E, ET);
        edge_denom_kernel<<<eb, blk, 0, stream>>>(src, dst, asrc, adst, m, den, E, ET);
        edge_accum_kernel<<<ab, blk, 0, stream>>>(src, dst, asrc, adst, m, den, H, A, E, ET);
        finalize_kernel<<<fb, blk, 0, stream>>>(A, b1, NN);

        transform_kernel<true, false><<<nb, blk, 0, stream>>>(A, W2, as2, ad2, nullptr,
                                                              H, asrc, adst, NN, 32);
        hipMemsetAsync(A, 0, NF * sizeof(float), stream);
        hipMemsetAsync(m, 0, NN * sizeof(int), stream);
        hipMemsetAsync(den, 0, NN * sizeof(float), stream);
        edge_max_kernel<<<eb, blk, 0, stream>>>(src, dst, asrc, adst, m, E, ET);
        edge_denom_kernel<<<eb, blk, 0, stream>>>(src, dst, asrc, adst, m, den, E, ET);
        edge_accum_kernel<<<ab, blk, 0, stream>>>(src, dst, asrc, adst, m, den, H, A, E, ET);
        finalize_kernel<<<fb, blk, 0, stream>>>(A, b2, NN);

        transform_kernel<false, true><<<nb, blk, 0, stream>>>(A, Wr, nullptr, nullptr, br,
                                                              out, nullptr, nullptr, NN, 32);
    }
}

// Round 5
// 452.282 us; speedup vs baseline: 3.1697x; 1.4943x over previous
//
#include <hip/hip_runtime.h>

#define NN 100000
#define NEG_SLOPE 0.2f
#define FOUT 32
#define CAP 128
#define BKT 256                       // dst-nodes per bucket
#define NBK ((NN + BKT - 1) / BKT)    // 391
#define CHUNK 8192

__device__ __forceinline__ float lrelu(float e) { return e > 0.f ? e : NEG_SLOPE * e; }

// ---------------- node transform: h = X @ W (+bias), optional attention dots ----------------
template <bool ATT, bool ADD_BIAS>
__global__ void transform_kernel(const float* __restrict__ X, const float* __restrict__ W,
                                 const float* __restrict__ att_s, const float* __restrict__ att_d,
                                 const float* __restrict__ bias,
                                 float* __restrict__ H, float* __restrict__ a_src,
                                 float* __restrict__ a_dst, int N, int Fin) {
    __shared__ float Wl[128 * FOUT];
    __shared__ float Xl[8 * 128];
    const int t = threadIdx.x;
    const int nodeBase = blockIdx.x * 8;
    const int vprW = Fin * FOUT / 4;
    for (int i = t; i < vprW; i += 256) ((float4*)Wl)[i] = ((const float4*)W)[i];
    const int vpr = Fin / 4;
    for (int i = t; i < 8 * vpr; i += 256) {
        int r = i / vpr, c = i - r * vpr;
        int n = nodeBase + r;
        ((float4*)Xl)[i] = (n < N) ? ((const float4*)X)[(size_t)n * vpr + c]
                                   : make_float4(0.f, 0.f, 0.f, 0.f);
    }
    __syncthreads();
    const int ln = t >> 5;
    const int j  = t & 31;
    const int n  = nodeBase + ln;
    float acc = 0.f;
    for (int k = 0; k < Fin; ++k)
        acc = fmaf(Xl[ln * Fin + k], Wl[k * FOUT + j], acc);
    if (ADD_BIAS) acc += bias[j];
    if (n < N) H[(size_t)n * FOUT + j] = acc;
    if (ATT) {
        float vs = acc * att_s[j];
        float vd = acc * att_d[j];
        #pragma unroll
        for (int m = 16; m >= 1; m >>= 1) {
            vs += __shfl_xor(vs, m, 32);
            vd += __shfl_xor(vd, m, 32);
        }
        if (j == 0 && n < N) { a_src[n] = vs; a_dst[n] = vd; }
    }
}

// ---------------- CSR build ----------------
__global__ void init_one_kernel(int* __restrict__ cnt, int n) {
    int i = blockIdx.x * blockDim.x + threadIdx.x;
    if (i < n) cnt[i] = 1;   // self loop
}

// per-node histogram; vectorized int4 path when E % 4 == 0
__global__ void hist_kernel(const int* __restrict__ dst, int E, int vec4,
                            int* __restrict__ cnt) {
    int i = blockIdx.x * blockDim.x + threadIdx.x;
    if (vec4) {
        int i4 = i * 4;
        if (i4 + 3 < E) {
            int4 d = *(const int4*)(dst + i4);
            atomicAdd(&cnt[d.x], 1); atomicAdd(&cnt[d.y], 1);
            atomicAdd(&cnt[d.z], 1); atomicAdd(&cnt[d.w], 1);
        }
    } else {
        if (i < E) atomicAdd(&cnt[dst[i]], 1);
    }
}

template <int BS>
__global__ void scan_blocks_kernel(const int* __restrict__ in, int n,
                                   int* __restrict__ out, int* __restrict__ bsums) {
    int g = blockIdx.x * BS + threadIdx.x;
    int v = (g < n) ? in[g] : 0;
    int lane = threadIdx.x & 63;
    int w = threadIdx.x >> 6;
    int x = v;
    #pragma unroll
    for (int o = 1; o < 64; o <<= 1) {
        int y = __shfl_up(x, o, 64);
        if (lane >= o) x += y;
    }
    __shared__ int ws[BS / 64];
    if (lane == 63) ws[w] = x;
    __syncthreads();
    if (threadIdx.x == 0) {
        int a = 0;
        for (int k = 0; k < BS / 64; ++k) { int tv = ws[k]; ws[k] = a; a += tv; }
        if (bsums) bsums[blockIdx.x] = a;
    }
    __syncthreads();
    int ex = x - v + ws[w];
    if (g < n) out[g] = ex;
}

__global__ void add_offsets_kernel(int* __restrict__ out, const int* __restrict__ bsums, int n) {
    int g = blockIdx.x * 256 + threadIdx.x;
    if (g < n) out[g] += bsums[blockIdx.x];
}

// bucket write-cursors: edge-only prefix (self-loops excluded): ptr[n] - n
__global__ void bcur_init_kernel(const int* __restrict__ ptr, int* __restrict__ bcur) {
    int b = blockIdx.x * blockDim.x + threadIdx.x;
    if (b < NBK) { int n = b * BKT; bcur[b] = ptr[n] - n; }
}

// pass 1: bin edges by dst bucket, packed (d_local<<17 | s), contiguous runs per (block,bucket)
__global__ __launch_bounds__(256)
void partition_kernel(const int* __restrict__ src, const int* __restrict__ dst, int E,
                      int* __restrict__ bcur, unsigned* __restrict__ pbuf) {
    __shared__ int hist[NBK];
    __shared__ int runbase[NBK];
    __shared__ int c2[NBK];
    const int tid = threadIdx.x;
    const int e0 = blockIdx.x * CHUNK;
    const int e1 = min(e0 + CHUNK, E);
    for (int t = tid; t < NBK; t += 256) { hist[t] = 0; c2[t] = 0; }
    __syncthreads();
    for (int i = e0 + tid; i < e1; i += 256)
        atomicAdd(&hist[((unsigned)dst[i]) >> 8], 1);
    __syncthreads();
    for (int t = tid; t < NBK; t += 256) {
        int h = hist[t];
        runbase[t] = h ? atomicAdd(&bcur[t], h) : 0;
    }
    __syncthreads();
    for (int i = e0 + tid; i < e1; i += 256) {
        int d = dst[i], s = src[i];
        int b = ((unsigned)d) >> 8;
        int ofs = atomicAdd(&c2[b], 1);
        pbuf[runbase[b] + ofs] = (((unsigned)(d & (BKT - 1))) << 17) | (unsigned)s;
    }
}

// pass 2: one block per bucket; LDS fill cursors; writes land in the bucket's
// contiguous ~35KB ssrc window (L2-merged). Also writes self-loops (slot 0).
__global__ __launch_bounds__(256)
void bucket_scatter_kernel(const int* __restrict__ ptr, const unsigned* __restrict__ pbuf,
                           int E, int* __restrict__ ssrc) {
    __shared__ int cur[BKT];
    const int b = blockIdx.x;
    const int tid = threadIdx.x;
    const int n0 = b * BKT;
    const int nodes = min(BKT, NN - n0);
    if (tid < nodes) {
        int p = ptr[n0 + tid];
        ssrc[p] = n0 + tid;      // self loop at slot 0
        cur[tid] = p + 1;
    }
    __syncthreads();
    const int bstart = ptr[n0] - n0;
    const int bend = (b == NBK - 1) ? E : ptr[n0 + BKT] - (n0 + BKT);
    for (int i = bstart + tid; i < bend; i += 256) {
        unsigned u = pbuf[i];
        int dl = u >> 17;
        int s  = (int)(u & 0x1FFFFu);
        int pos = atomicAdd(&cur[dl], 1);
        ssrc[pos] = s;
    }
}

__global__ void copy_kernel(const int* __restrict__ in, int* __restrict__ out, int n) {
    int i = blockIdx.x * blockDim.x + threadIdx.x;
    if (i < n) out[i] = in[i];
}

// tier-2 simple scatter (plain store; cfill pre-initialized to ptr)
__global__ void scatter_kernel(const int* __restrict__ src, const int* __restrict__ dst,
                               int E, int ET, int* __restrict__ cfill, int* __restrict__ ssrc) {
    int i = blockIdx.x * blockDim.x + threadIdx.x;
    if (i >= ET) return;
    int s, d;
    if (i < E) { s = src[i]; d = dst[i]; }
    else       { s = d = i - E; }
    int pos = atomicAdd(&cfill[d], 1);
    ssrc[pos] = s;
}

// ---------------- fused per-node GAT aggregation (CSR gather) ----------------
template <bool FUSE_OUT>
__global__ __launch_bounds__(256)
void gat_csr_kernel(const int* __restrict__ ptr, const int* __restrict__ ssrc,
                    const float* __restrict__ asrc, const float* __restrict__ adst,
                    const float* __restrict__ H, const float* __restrict__ bias,
                    const float* __restrict__ Wr, const float* __restrict__ br,
                    float* __restrict__ out, int ET) {
    __shared__ float Wl[32 * 32];
    __shared__ float ebuf[4][CAP];
    __shared__ int   sbuf[4][CAP];
    const int tid = threadIdx.x;
    if (FUSE_OUT) {
        for (int i = tid; i < 1024; i += 256) Wl[i] = Wr[i];
    }
    const int w = tid >> 6, lane = tid & 63;
    const int wid = blockIdx.x * 4 + w;
    const int beg = ptr[wid];
    const int end = (wid == NN - 1) ? ET : ptr[wid + 1];
    const int deg = end - beg;
    const int cap = min(deg, CAP);
    const float ad = adst[wid];

    // pass A: load edges once, cache (s,e) in LDS, track max
    float mx = -1e30f;
    for (int k = lane; k < cap; k += 64) {
        int s = ssrc[beg + k];
        float e = lrelu(asrc[s] + ad);
        sbuf[w][k] = s; ebuf[w][k] = e;
        mx = fmaxf(mx, e);
    }
    for (int k = cap + lane; k < deg; k += 64) {
        int s = ssrc[beg + k];
        mx = fmaxf(mx, lrelu(asrc[s] + ad));
    }
    #pragma unroll
    for (int o = 32; o; o >>= 1) mx = fmaxf(mx, __shfl_xor(mx, o, 64));

    __syncthreads();

    // pass B: denom
    float sm = 0.f;
    for (int k = lane; k < cap; k += 64) sm += __expf(ebuf[w][k] - mx);
    for (int k = cap + lane; k < deg; k += 64) {
        int s = ssrc[beg + k];
        sm += __expf(lrelu(asrc[s] + ad) - mx);
    }
    #pragma unroll
    for (int o = 32; o; o >>= 1) sm += __shfl_xor(sm, o, 64);
    const float inv = 1.f / (sm + 1e-16f);

    // pass C: quarter q handles edges k === q (mod 4); lane t holds features (2t, 2t+1)
    const int q = lane >> 4, t = lane & 15;
    float ax0 = 0.f, ay0 = 0.f, ax1 = 0.f, ay1 = 0.f;
    int k = q;
    for (; k + 4 < deg; k += 8) {
        int s0; float e0;
        if (k < cap) { s0 = sbuf[w][k]; e0 = ebuf[w][k]; }
        else         { s0 = ssrc[beg + k]; e0 = lrelu(asrc[s0] + ad); }
        int k1 = k + 4; int s1; float e1;
        if (k1 < cap) { s1 = sbuf[w][k1]; e1 = ebuf[w][k1]; }
        else          { s1 = ssrc[beg + k1]; e1 = lrelu(asrc[s1] + ad); }
        float w0 = __expf(e0 - mx), w1 = __expf(e1 - mx);
        float2 h0 = *(const float2*)(H + (size_t)s0 * FOUT + 2 * t);
        float2 h1 = *(const float2*)(H + (size_t)s1 * FOUT + 2 * t);
        ax0 = fmaf(w0, h0.x, ax0); ay0 = fmaf(w0, h0.y, ay0);
        ax1 = fmaf(w1, h1.x, ax1); ay1 = fmaf(w1, h1.y, ay1);
    }
    for (; k < deg; k += 4) {
        int s; float e;
        if (k < cap) { s = sbuf[w][k]; e = ebuf[w][k]; }
        else         { s = ssrc[beg + k]; e = lrelu(asrc[s] + ad); }
        float w0 = __expf(e - mx);
        float2 h = *(const float2*)(H + (size_t)s * FOUT + 2 * t);
        ax0 = fmaf(w0, h.x, ax0); ay0 = fmaf(w0, h.y, ay0);
    }
    float ax = ax0 + ax1, ay = ay0 + ay1;
    ax += __shfl_xor(ax, 16, 64); ay += __shfl_xor(ay, 16, 64);
    ax += __shfl_xor(ax, 32, 64); ay += __shfl_xor(ay, 32, 64);

    if (!FUSE_OUT) {
        if (lane < 16) {
            float vx = fmaxf(ax * inv + bias[2 * t],     0.f);
            float vy = fmaxf(ay * inv + bias[2 * t + 1], 0.f);
            *(float2*)(out + (size_t)wid * FOUT + 2 * t) = make_float2(vx, vy);
        }
    } else {
        if (lane < 16) {
            ebuf[w][2 * t]     = fmaxf(ax * inv + bias[2 * t],     0.f);
            ebuf[w][2 * t + 1] = fmaxf(ay * inv + bias[2 * t + 1], 0.f);
        }
        __syncthreads();
        if (lane < 16) {
            float rx = br[2 * t], ry = br[2 * t + 1];
            #pragma unroll
            for (int j = 0; j < 32; ++j) {
                float hj = ebuf[w][j];
                rx = fmaf(hj, Wl[j * 32 + 2 * t],     rx);
                ry = fmaf(hj, Wl[j * 32 + 2 * t + 1], ry);
            }
            *(float2*)(out + (size_t)wid * FOUT + 2 * t) = make_float2(rx, ry);
        }
    }
}

// ---------------- tier-3 fallback (round-2 proven atomic path) ----------------
__device__ __forceinline__ unsigned ordf(float f) {
    unsigned u = __float_as_uint(f);
    return (u & 0x80000000u) ? ~u : (u | 0x80000000u);
}
__device__ __forceinline__ float unordf(unsigned u) {
    return (u & 0x80000000u) ? __uint_as_float(u & 0x7FFFFFFFu) : __uint_as_float(~u);
}
__device__ __forceinline__ void edge_sd(int i, int E, const int* __restrict__ src,
                                        const int* __restrict__ dst, int& s, int& d) {
    if (i < E) { s = src[i]; d = dst[i]; }
    else       { s = d = i - E; }
}
__global__ void edge_max_kernel(const int* __restrict__ src, const int* __restrict__ dst,
                                const float* __restrict__ a_src, const float* __restrict__ a_dst,
                                unsigned* __restrict__ m, int E, int ET) {
    int i = blockIdx.x * blockDim.x + threadIdx.x;
    if (i >= ET) return;
    int s, d; edge_sd(i, E, src, dst, s, d);
    atomicMax(m + d, ordf(lrelu(a_src[s] + a_dst[d])));
}
__global__ void edge_denom_kernel(const int* __restrict__ src, const int* __restrict__ dst,
                                  const float* __restrict__ a_src, const float* __restrict__ a_dst,
                                  const unsigned* __restrict__ m, float* __restrict__ denom,
                                  int E, int ET) {
    int i = blockIdx.x * blockDim.x + threadIdx.x;
    if (i >= ET) return;
    int s, d; edge_sd(i, E, src, dst, s, d);
    atomicAdd(denom + d, __expf(lrelu(a_src[s] + a_dst[d]) - unordf(m[d])));
}
__global__ void edge_accum_kernel(const int* __restrict__ src, const int* __restrict__ dst,
                                  const float* __restrict__ a_src, const float* __restrict__ a_dst,
                                  const unsigned* __restrict__ m, const float* __restrict__ denom,
                                  const float* __restrict__ H, float* __restrict__ accum,
                                  int E, int ET) {
    long tid = (long)blockIdx.x * blockDim.x + threadIdx.x;
    if (tid >= (long)ET * FOUT) return;
    int i = (int)(tid >> 5);
    int j = (int)(tid & 31);
    int s, d; edge_sd(i, E, src, dst, s, d);
    float w = __expf(lrelu(a_src[s] + a_dst[d]) - unordf(m[d])) / (denom[d] + 1e-16f);
    atomicAdd(accum + (long)d * FOUT + j, w * H[(long)s * FOUT + j]);
}
__global__ void finalize_kernel(float* __restrict__ accum, const float* __restrict__ bias, int N) {
    int tid = blockIdx.x * blockDim.x + threadIdx.x;
    if (tid >= N * FOUT) return;
    int j = tid & 31;
    accum[tid] = fmaxf(accum[tid] + bias[j], 0.f);
}

extern "C" void kernel_launch(void* const* d_in, const int* in_sizes, int n_in,
                              void* d_out, int out_size, void* d_ws, size_t ws_size,
                              hipStream_t stream) {
    const float* x   = (const float*)d_in[0];
    const int*   ei  = (const int*)d_in[1];
    const float* W1  = (const float*)d_in[2];
    const float* as1 = (const float*)d_in[3];
    const float* ad1 = (const float*)d_in[4];
    const float* b1  = (const float*)d_in[5];
    const float* W2  = (const float*)d_in[6];
    const float* as2 = (const float*)d_in[7];
    const float* ad2 = (const float*)d_in[8];
    const float* b2  = (const float*)d_in[9];
    const float* Wr  = (const float*)d_in[10];
    const float* br  = (const float*)d_in[11];
    float* out = (float*)d_out;

    const int E  = in_sizes[1] / 2;
    const int*  src = ei;
    const int*  dst = ei + E;
    const int ET = E + NN;

    const size_t NF = (size_t)NN * FOUT;
    // layout: A(NF) | H(NF) | asrc(NN) | adst(NN) | ptr(NN) | cnt/bcur(NN) | bsum(512) | ssrc(ET)
    float* A     = (float*)d_ws;
    float* H     = A + NF;
    float* asrc  = H + NF;
    float* adst  = asrc + NN;
    int*   ptr   = (int*)(adst + NN);
    int*   cnt   = ptr + NN;          // also: bucket cursors (tier1), fill cursors (tier2)
    int*   bsum  = cnt + NN;
    int*   ssrc  = bsum + 512;
    const size_t need = (2 * NF + 4 * (size_t)NN + 512 + (size_t)ET) * 4;

    dim3 blk(256);
    const int nb  = (NN + 7) / 8;
    const int fb  = (NN * FOUT + 255) / 256;
    const int nb1 = (NN + 255) / 256;   // 391

    if (ws_size >= need) {
        // ================= CSR gather path =================
        const int gb = NN / 4;   // 25000 blocks, 4 waves each

        // per-node counts (self loop = 1) -> exclusive scan -> ptr
        init_one_kernel<<<nb1, blk, 0, stream>>>(cnt, NN);
        const int vec4 = ((E & 3) == 0) ? 1 : 0;
        const int hb = vec4 ? (E / 4 + 255) / 256 : (E + 255) / 256;
        hist_kernel<<<hb, blk, 0, stream>>>(dst, E, vec4, cnt);
        scan_blocks_kernel<256><<<nb1, blk, 0, stream>>>(cnt, NN, ptr, bsum);
        scan_blocks_kernel<512><<<1, 512, 0, stream>>>(bsum, nb1, bsum, nullptr);
        add_offsets_kernel<<<nb1, blk, 0, stream>>>(ptr, bsum, NN);

        if ((size_t)E <= NF) {
            // tier 1: two-phase binned scatter (pbuf reuses A)
            unsigned* pbuf = (unsigned*)A;
            bcur_init_kernel<<<(NBK + 255) / 256, blk, 0, stream>>>(ptr, cnt);
            partition_kernel<<<(E + CHUNK - 1) / CHUNK, blk, 0, stream>>>(src, dst, E, cnt, pbuf);
            bucket_scatter_kernel<<<NBK, blk, 0, stream>>>(ptr, pbuf, E, ssrc);
        } else {
            // tier 2: simple scatter
            copy_kernel<<<nb1, blk, 0, stream>>>(ptr, cnt, NN);
            scatter_kernel<<<(ET + 255) / 256, blk, 0, stream>>>(src, dst, E, ET, cnt, ssrc);
        }

        // layer 1
        transform_kernel<true, false><<<nb, blk, 0, stream>>>(x, W1, as1, ad1, nullptr,
                                                              H, asrc, adst, NN, 128);
        gat_csr_kernel<false><<<gb, blk, 0, stream>>>(ptr, ssrc, asrc, adst, H, b1,
                                                      nullptr, nullptr, A, ET);
        // layer 2 + fused readout
        transform_kernel<true, false><<<nb, blk, 0, stream>>>(A, W2, as2, ad2, nullptr,
                                                              H, asrc, adst, NN, 32);
        gat_csr_kernel<true><<<gb, blk, 0, stream>>>(ptr, ssrc, asrc, adst, H, b2,
                                                     Wr, br, out, ET);
    } else {
        // ================= tier 3: atomic path =================
        unsigned* m   = (unsigned*)ptr;
        float*    den = (float*)cnt;
        const int eb = (ET + 255) / 256;
        const int ab = (int)(((long)ET * FOUT + 255) / 256);

        hipMemsetAsync(A, 0, NF * sizeof(float), stream);
        hipMemsetAsync(m, 0, NN * sizeof(int), stream);
        hipMemsetAsync(den, 0, NN * sizeof(float), stream);
        transform_kernel<true, false><<<nb, blk, 0, stream>>>(x, W1, as1, ad1, nullptr,
                                                              H, asrc, adst, NN, 128);
        edge_max_kernel<<<eb, blk, 0, stream>>>(src, dst, asrc, adst, m, E, ET);
        edge_denom_kernel<<<eb, blk, 0, stream>>>(src, dst, asrc, adst, m, den, E, ET);
        edge_accum_kernel<<<ab, blk, 0, stream>>>(src, dst, asrc, adst, m, den, H, A, E, ET);
        finalize_kernel<<<fb, blk, 0, stream>>>(A, b1, NN);

        transform_kernel<true, false><<<nb, blk, 0, stream>>>(A, W2, as2, ad2, nullptr,
                                                              H, asrc, adst, NN, 32);
        hipMemsetAsync(A, 0, NF * sizeof(float), stream);
        hipMemsetAsync(m, 0, NN * sizeof(int), stream);
        hipMemsetAsync(den, 0, NN * sizeof(float), stream);
        edge_max_kernel<<<eb, blk, 0, stream>>>(src, dst, asrc, adst, m, E, ET);
        edge_denom_kernel<<<eb, blk, 0, stream>>>(src, dst, asrc, adst, m, den, E, ET);
        edge_accum_kernel<<<ab, blk, 0, stream>>>(src, dst, asrc, adst, m, den, H, A, E, ET);
        finalize_kernel<<<fb, blk, 0, stream>>>(A, b2, NN);

        transform_kernel<false, true><<<nb, blk, 0, stream>>>(A, Wr, nullptr, nullptr, br,
                                                              out, nullptr, nullptr, NN, 32);
    }
}

// Round 6
// 340.037 us; speedup vs baseline: 4.2160x; 1.3301x over previous
//
#include <hip/hip_runtime.h>

#define NN 100000
#define NEG_SLOPE 0.2f
#define FOUT 32
#define CAP 128
#define BKT 256                       // dst-nodes per bucket
#define NBK ((NN + BKT - 1) / BKT)    // 391
#define CHUNK 8192

__device__ __forceinline__ float lrelu(float e) { return e > 0.f ? e : NEG_SLOPE * e; }

// ---------------- node transform: h = X @ W (+bias), optional attention dots ----------------
template <bool ATT, bool ADD_BIAS>
__global__ void transform_kernel(const float* __restrict__ X, const float* __restrict__ W,
                                 const float* __restrict__ att_s, const float* __restrict__ att_d,
                                 const float* __restrict__ bias,
                                 float* __restrict__ H, float* __restrict__ a_src,
                                 float* __restrict__ a_dst, int N, int Fin) {
    __shared__ float Wl[128 * FOUT];
    __shared__ float Xl[8 * 128];
    const int t = threadIdx.x;
    const int nodeBase = blockIdx.x * 8;
    const int vprW = Fin * FOUT / 4;
    for (int i = t; i < vprW; i += 256) ((float4*)Wl)[i] = ((const float4*)W)[i];
    const int vpr = Fin / 4;
    for (int i = t; i < 8 * vpr; i += 256) {
        int r = i / vpr, c = i - r * vpr;
        int n = nodeBase + r;
        ((float4*)Xl)[i] = (n < N) ? ((const float4*)X)[(size_t)n * vpr + c]
                                   : make_float4(0.f, 0.f, 0.f, 0.f);
    }
    __syncthreads();
    const int ln = t >> 5;
    const int j  = t & 31;
    const int n  = nodeBase + ln;
    float acc = 0.f;
    for (int k = 0; k < Fin; ++k)
        acc = fmaf(Xl[ln * Fin + k], Wl[k * FOUT + j], acc);
    if (ADD_BIAS) acc += bias[j];
    if (n < N) H[(size_t)n * FOUT + j] = acc;
    if (ATT) {
        float vs = acc * att_s[j];
        float vd = acc * att_d[j];
        #pragma unroll
        for (int m = 16; m >= 1; m >>= 1) {
            vs += __shfl_xor(vs, m, 32);
            vd += __shfl_xor(vd, m, 32);
        }
        if (j == 0 && n < N) { a_src[n] = vs; a_dst[n] = vd; }
    }
}

// ---------------- CSR build (tier-1: hierarchical, no per-node global atomics) -------------
// pass 0: per-bucket edge counts; LDS hist -> one global atomic per (block,bucket)
__global__ __launch_bounds__(256)
void bucket_count_kernel(const int* __restrict__ dst, int E, int* __restrict__ bktcnt) {
    __shared__ int hist[NBK];
    const int tid = threadIdx.x;
    const int e0 = blockIdx.x * CHUNK;
    const int e1 = min(e0 + CHUNK, E);
    for (int t = tid; t < NBK; t += 256) hist[t] = 0;
    __syncthreads();
    for (int i = e0 + tid; i < e1; i += 256)
        atomicAdd(&hist[((unsigned)dst[i]) >> 8], 1);
    __syncthreads();
    for (int t = tid; t < NBK; t += 256) {
        int h = hist[t];
        if (h) atomicAdd(&bktcnt[t], h);
    }
}

template <int BS>
__global__ void scan_blocks_kernel(const int* __restrict__ in, int n,
                                   int* __restrict__ out, int* __restrict__ bsums) {
    int g = blockIdx.x * BS + threadIdx.x;
    int v = (g < n) ? in[g] : 0;
    int lane = threadIdx.x & 63;
    int w = threadIdx.x >> 6;
    int x = v;
    #pragma unroll
    for (int o = 1; o < 64; o <<= 1) {
        int y = __shfl_up(x, o, 64);
        if (lane >= o) x += y;
    }
    __shared__ int ws[BS / 64];
    if (lane == 63) ws[w] = x;
    __syncthreads();
    if (threadIdx.x == 0) {
        int a = 0;
        for (int k = 0; k < BS / 64; ++k) { int tv = ws[k]; ws[k] = a; a += tv; }
        if (bsums) bsums[blockIdx.x] = a;
    }
    __syncthreads();
    int ex = x - v + ws[w];
    if (g < n) out[g] = ex;
}

__global__ void add_offsets_kernel(int* __restrict__ out, const int* __restrict__ bsums, int n) {
    int g = blockIdx.x * 256 + threadIdx.x;
    if (g < n) out[g] += bsums[blockIdx.x];
}

__global__ void copy_kernel(const int* __restrict__ in, int* __restrict__ out, int n) {
    int i = blockIdx.x * blockDim.x + threadIdx.x;
    if (i < n) out[i] = in[i];
}

// pass 1: bin edges by dst bucket, packed (d_local<<17 | s), contiguous runs per (block,bucket)
__global__ __launch_bounds__(256)
void partition_kernel(const int* __restrict__ src, const int* __restrict__ dst, int E,
                      int* __restrict__ bcur, unsigned* __restrict__ pbuf) {
    __shared__ int hist[NBK];
    __shared__ int runbase[NBK];
    __shared__ int c2[NBK];
    const int tid = threadIdx.x;
    const int e0 = blockIdx.x * CHUNK;
    const int e1 = min(e0 + CHUNK, E);
    for (int t = tid; t < NBK; t += 256) { hist[t] = 0; c2[t] = 0; }
    __syncthreads();
    for (int i = e0 + tid; i < e1; i += 256)
        atomicAdd(&hist[((unsigned)dst[i]) >> 8], 1);
    __syncthreads();
    for (int t = tid; t < NBK; t += 256) {
        int h = hist[t];
        runbase[t] = h ? atomicAdd(&bcur[t], h) : 0;
    }
    __syncthreads();
    for (int i = e0 + tid; i < e1; i += 256) {
        int d = dst[i], s = src[i];
        int b = ((unsigned)d) >> 8;
        int ofs = atomicAdd(&c2[b], 1);
        pbuf[runbase[b] + ofs] = (((unsigned)(d & (BKT - 1))) << 17) | (unsigned)s;
    }
}

// pass 2: one block per bucket. Local per-node counts (LDS atomics) + LDS scan
// -> writes ptr AND ssrc (self-loop at slot 0). All scatter writes land in the
// bucket's contiguous ~32KB window (L2-merged).
__global__ __launch_bounds__(256)
void bucket_scatter_kernel(const int* __restrict__ bktbase, const unsigned* __restrict__ pbuf,
                           int E, int* __restrict__ ptr, int* __restrict__ ssrc) {
    __shared__ int lcnt[BKT];
    __shared__ int cur[BKT];
    __shared__ int wsum[4];
    const int b = blockIdx.x;
    const int tid = threadIdx.x;
    const int n0 = b * BKT;
    const int nodes = min(BKT, NN - n0);
    const int bstart = bktbase[b];
    const int bend = (b == NBK - 1) ? E : bktbase[b + 1];
    lcnt[tid] = 0;
    __syncthreads();
    for (int i = bstart + tid; i < bend; i += 256)
        atomicAdd(&lcnt[pbuf[i] >> 17], 1);
    __syncthreads();
    // exclusive scan of (lcnt[t] + 1) over the block (self loop included)
    int v = (tid < nodes) ? (lcnt[tid] + 1) : 0;
    int lane = tid & 63, w = tid >> 6;
    int x = v;
    #pragma unroll
    for (int o = 1; o < 64; o <<= 1) {
        int y = __shfl_up(x, o, 64);
        if (lane >= o) x += y;
    }
    if (lane == 63) wsum[w] = x;
    __syncthreads();
    if (tid == 0) {
        int a = 0;
        #pragma unroll
        for (int k = 0; k < 4; ++k) { int t2 = wsum[k]; wsum[k] = a; a += t2; }
    }
    __syncthreads();
    int ex = x - v + wsum[w];
    if (tid < nodes) {
        int p = bstart + n0 + ex;       // edges before bucket + self loops before bucket + local
        ptr[n0 + tid] = p;
        ssrc[p] = n0 + tid;             // self loop at slot 0
        cur[tid] = p + 1;
    }
    __syncthreads();
    for (int i = bstart + tid; i < bend; i += 256) {
        unsigned u = pbuf[i];
        int pos = atomicAdd(&cur[u >> 17], 1);
        ssrc[pos] = (int)(u & 0x1FFFFu);
    }
}

// ---------------- tier-2 helpers (per-node hist path, fallback only) ----------------
__global__ void init_one_kernel(int* __restrict__ cnt, int n) {
    int i = blockIdx.x * blockDim.x + threadIdx.x;
    if (i < n) cnt[i] = 1;
}
__global__ void hist_kernel(const int* __restrict__ dst, int E, int* __restrict__ cnt) {
    int i = blockIdx.x * blockDim.x + threadIdx.x;
    if (i < E) atomicAdd(&cnt[dst[i]], 1);
}
__global__ void scatter_kernel(const int* __restrict__ src, const int* __restrict__ dst,
                               int E, int ET, int* __restrict__ cfill, int* __restrict__ ssrc) {
    int i = blockIdx.x * blockDim.x + threadIdx.x;
    if (i >= ET) return;
    int s, d;
    if (i < E) { s = src[i]; d = dst[i]; }
    else       { s = d = i - E; }
    int pos = atomicAdd(&cfill[d], 1);
    ssrc[pos] = s;
}

// ---------------- fused per-node GAT aggregation (CSR gather) ----------------
template <bool FUSE_OUT>
__global__ __launch_bounds__(256)
void gat_csr_kernel(const int* __restrict__ ptr, const int* __restrict__ ssrc,
                    const float* __restrict__ asrc, const float* __restrict__ adst,
                    const float* __restrict__ H, const float* __restrict__ bias,
                    const float* __restrict__ Wr, const float* __restrict__ br,
                    float* __restrict__ out, int ET) {
    __shared__ float Wl[32 * 32];
    __shared__ float ebuf[4][CAP];
    __shared__ int   sbuf[4][CAP];
    const int tid = threadIdx.x;
    if (FUSE_OUT) {
        for (int i = tid; i < 1024; i += 256) Wl[i] = Wr[i];
    }
    const int w = tid >> 6, lane = tid & 63;
    const int wid = blockIdx.x * 4 + w;
    const int beg = ptr[wid];
    const int end = (wid == NN - 1) ? ET : ptr[wid + 1];
    const int deg = end - beg;
    const int cap = min(deg, CAP);
    const float ad = adst[wid];

    // pass A: load edges once, cache (s,e) in LDS, track max
    float mx = -1e30f;
    for (int k = lane; k < cap; k += 64) {
        int s = ssrc[beg + k];
        float e = lrelu(asrc[s] + ad);
        sbuf[w][k] = s; ebuf[w][k] = e;
        mx = fmaxf(mx, e);
    }
    for (int k = cap + lane; k < deg; k += 64) {
        int s = ssrc[beg + k];
        mx = fmaxf(mx, lrelu(asrc[s] + ad));
    }
    #pragma unroll
    for (int o = 32; o; o >>= 1) mx = fmaxf(mx, __shfl_xor(mx, o, 64));

    __syncthreads();

    // pass B: denom
    float sm = 0.f;
    for (int k = lane; k < cap; k += 64) sm += __expf(ebuf[w][k] - mx);
    for (int k = cap + lane; k < deg; k += 64) {
        int s = ssrc[beg + k];
        sm += __expf(lrelu(asrc[s] + ad) - mx);
    }
    #pragma unroll
    for (int o = 32; o; o >>= 1) sm += __shfl_xor(sm, o, 64);
    const float inv = 1.f / (sm + 1e-16f);

    // pass C: quarter q handles edges k === q (mod 4); lane t holds features (2t, 2t+1)
    const int q = lane >> 4, t = lane & 15;
    float ax0 = 0.f, ay0 = 0.f, ax1 = 0.f, ay1 = 0.f;
    int k = q;
    for (; k + 4 < deg; k += 8) {
        int s0; float e0;
        if (k < cap) { s0 = sbuf[w][k]; e0 = ebuf[w][k]; }
        else         { s0 = ssrc[beg + k]; e0 = lrelu(asrc[s0] + ad); }
        int k1 = k + 4; int s1; float e1;
        if (k1 < cap) { s1 = sbuf[w][k1]; e1 = ebuf[w][k1]; }
        else          { s1 = ssrc[beg + k1]; e1 = lrelu(asrc[s1] + ad); }
        float w0 = __expf(e0 - mx), w1 = __expf(e1 - mx);
        float2 h0 = *(const float2*)(H + (size_t)s0 * FOUT + 2 * t);
        float2 h1 = *(const float2*)(H + (size_t)s1 * FOUT + 2 * t);
        ax0 = fmaf(w0, h0.x, ax0); ay0 = fmaf(w0, h0.y, ay0);
        ax1 = fmaf(w1, h1.x, ax1); ay1 = fmaf(w1, h1.y, ay1);
    }
    for (; k < deg; k += 4) {
        int s; float e;
        if (k < cap) { s = sbuf[w][k]; e = ebuf[w][k]; }
        else         { s = ssrc[beg + k]; e = lrelu(asrc[s] + ad); }
        float w0 = __expf(e - mx);
        float2 h = *(const float2*)(H + (size_t)s * FOUT + 2 * t);
        ax0 = fmaf(w0, h.x, ax0); ay0 = fmaf(w0, h.y, ay0);
    }
    float ax = ax0 + ax1, ay = ay0 + ay1;
    ax += __shfl_xor(ax, 16, 64); ay += __shfl_xor(ay, 16, 64);
    ax += __shfl_xor(ax, 32, 64); ay += __shfl_xor(ay, 32, 64);

    if (!FUSE_OUT) {
        if (lane < 16) {
            float vx = fmaxf(ax * inv + bias[2 * t],     0.f);
            float vy = fmaxf(ay * inv + bias[2 * t + 1], 0.f);
            *(float2*)(out + (size_t)wid * FOUT + 2 * t) = make_float2(vx, vy);
        }
    } else {
        if (lane < 16) {
            ebuf[w][2 * t]     = fmaxf(ax * inv + bias[2 * t],     0.f);
            ebuf[w][2 * t + 1] = fmaxf(ay * inv + bias[2 * t + 1], 0.f);
        }
        __syncthreads();
        if (lane < 16) {
            float rx = br[2 * t], ry = br[2 * t + 1];
            #pragma unroll
            for (int j = 0; j < 32; ++j) {
                float hj = ebuf[w][j];
                rx = fmaf(hj, Wl[j * 32 + 2 * t],     rx);
                ry = fmaf(hj, Wl[j * 32 + 2 * t + 1], ry);
            }
            *(float2*)(out + (size_t)wid * FOUT + 2 * t) = make_float2(rx, ry);
        }
    }
}

// ---------------- tier-3 fallback (round-2 proven atomic path) ----------------
__device__ __forceinline__ unsigned ordf(float f) {
    unsigned u = __float_as_uint(f);
    return (u & 0x80000000u) ? ~u : (u | 0x80000000u);
}
__device__ __forceinline__ float unordf(unsigned u) {
    return (u & 0x80000000u) ? __uint_as_float(u & 0x7FFFFFFFu) : __uint_as_float(~u);
}
__device__ __forceinline__ void edge_sd(int i, int E, const int* __restrict__ src,
                                        const int* __restrict__ dst, int& s, int& d) {
    if (i < E) { s = src[i]; d = dst[i]; }
    else       { s = d = i - E; }
}
__global__ void edge_max_kernel(const int* __restrict__ src, const int* __restrict__ dst,
                                const float* __restrict__ a_src, const float* __restrict__ a_dst,
                                unsigned* __restrict__ m, int E, int ET) {
    int i = blockIdx.x * blockDim.x + threadIdx.x;
    if (i >= ET) return;
    int s, d; edge_sd(i, E, src, dst, s, d);
    atomicMax(m + d, ordf(lrelu(a_src[s] + a_dst[d])));
}
__global__ void edge_denom_kernel(const int* __restrict__ src, const int* __restrict__ dst,
                                  const float* __restrict__ a_src, const float* __restrict__ a_dst,
                                  const unsigned* __restrict__ m, float* __restrict__ denom,
                                  int E, int ET) {
    int i = blockIdx.x * blockDim.x + threadIdx.x;
    if (i >= ET) return;
    int s, d; edge_sd(i, E, src, dst, s, d);
    atomicAdd(denom + d, __expf(lrelu(a_src[s] + a_dst[d]) - unordf(m[d])));
}
__global__ void edge_accum_kernel(const int* __restrict__ src, const int* __restrict__ dst,
                                  const float* __restrict__ a_src, const float* __restrict__ a_dst,
                                  const unsigned* __restrict__ m, const float* __restrict__ denom,
                                  const float* __restrict__ H, float* __restrict__ accum,
                                  int E, int ET) {
    long tid = (long)blockIdx.x * blockDim.x + threadIdx.x;
    if (tid >= (long)ET * FOUT) return;
    int i = (int)(tid >> 5);
    int j = (int)(tid & 31);
    int s, d; edge_sd(i, E, src, dst, s, d);
    float w = __expf(lrelu(a_src[s] + a_dst[d]) - unordf(m[d])) / (denom[d] + 1e-16f);
    atomicAdd(accum + (long)d * FOUT + j, w * H[(long)s * FOUT + j]);
}
__global__ void finalize_kernel(float* __restrict__ accum, const float* __restrict__ bias, int N) {
    int tid = blockIdx.x * blockDim.x + threadIdx.x;
    if (tid >= N * FOUT) return;
    int j = tid & 31;
    accum[tid] = fmaxf(accum[tid] + bias[j], 0.f);
}

extern "C" void kernel_launch(void* const* d_in, const int* in_sizes, int n_in,
                              void* d_out, int out_size, void* d_ws, size_t ws_size,
                              hipStream_t stream) {
    const float* x   = (const float*)d_in[0];
    const int*   ei  = (const int*)d_in[1];
    const float* W1  = (const float*)d_in[2];
    const float* as1 = (const float*)d_in[3];
    const float* ad1 = (const float*)d_in[4];
    const float* b1  = (const float*)d_in[5];
    const float* W2  = (const float*)d_in[6];
    const float* as2 = (const float*)d_in[7];
    const float* ad2 = (const float*)d_in[8];
    const float* b2  = (const float*)d_in[9];
    const float* Wr  = (const float*)d_in[10];
    const float* br  = (const float*)d_in[11];
    float* out = (float*)d_out;

    const int E  = in_sizes[1] / 2;
    const int*  src = ei;
    const int*  dst = ei + E;
    const int ET = E + NN;

    const size_t NF = (size_t)NN * FOUT;
    // layout: A(NF) | H(NF) | asrc(NN) | adst(NN) | ptr(NN) | cnt(NN) | bsum(512) | ssrc(ET)
    float* A     = (float*)d_ws;
    float* H     = A + NF;
    float* asrc  = H + NF;
    float* adst  = asrc + NN;
    int*   ptr   = (int*)(adst + NN);
    int*   cnt   = ptr + NN;
    int*   bsum  = cnt + NN;
    int*   ssrc  = bsum + 512;
    const size_t need = (2 * NF + 4 * (size_t)NN + 512 + (size_t)ET) * 4;

    dim3 blk(256);
    const int nb  = (NN + 7) / 8;
    const int fb  = (NN * FOUT + 255) / 256;
    const int nb1 = (NN + 255) / 256;   // 391

    if (ws_size >= need && (size_t)E <= NF) {
        // ================= tier 1: hierarchical CSR, no per-node global atomics ==========
        unsigned* pbuf    = (unsigned*)A;       // E entries (A is dead during CSR build)
        int*      bktcnt  = cnt;                // NBK
        int*      bktbase = cnt + 512;          // NBK
        int*      bcur    = cnt + 1024;         // NBK
        const int cb = (E + CHUNK - 1) / CHUNK; // 391 chunk blocks
        const int gb = NN / 4;                  // gat blocks

        hipMemsetAsync(bktcnt, 0, NBK * sizeof(int), stream);
        bucket_count_kernel<<<cb, blk, 0, stream>>>(dst, E, bktcnt);
        scan_blocks_kernel<512><<<1, 512, 0, stream>>>(bktcnt, NBK, bktbase, nullptr);
        copy_kernel<<<(NBK + 255) / 256, blk, 0, stream>>>(bktbase, bcur, NBK);
        partition_kernel<<<cb, blk, 0, stream>>>(src, dst, E, bcur, pbuf);
        bucket_scatter_kernel<<<NBK, blk, 0, stream>>>(bktbase, pbuf, E, ptr, ssrc);

        // layer 1
        transform_kernel<true, false><<<nb, blk, 0, stream>>>(x, W1, as1, ad1, nullptr,
                                                              H, asrc, adst, NN, 128);
        gat_csr_kernel<false><<<gb, blk, 0, stream>>>(ptr, ssrc, asrc, adst, H, b1,
                                                      nullptr, nullptr, A, ET);
        // layer 2 + fused readout
        transform_kernel<true, false><<<nb, blk, 0, stream>>>(A, W2, as2, ad2, nullptr,
                                                              H, asrc, adst, NN, 32);
        gat_csr_kernel<true><<<gb, blk, 0, stream>>>(ptr, ssrc, asrc, adst, H, b2,
                                                     Wr, br, out, ET);
    } else if (ws_size >= need) {
        // ================= tier 2: per-node hist + simple scatter =================
        const int gb = NN / 4;
        init_one_kernel<<<nb1, blk, 0, stream>>>(cnt, NN);
        hist_kernel<<<(E + 255) / 256, blk, 0, stream>>>(dst, E, cnt);
        scan_blocks_kernel<256><<<nb1, blk, 0, stream>>>(cnt, NN, ptr, bsum);
        scan_blocks_kernel<512><<<1, 512, 0, stream>>>(bsum, nb1, bsum, nullptr);
        add_offsets_kernel<<<nb1, blk, 0, stream>>>(ptr, bsum, NN);
        copy_kernel<<<nb1, blk, 0, stream>>>(ptr, cnt, NN);
        scatter_kernel<<<(ET + 255) / 256, blk, 0, stream>>>(src, dst, E, ET, cnt, ssrc);

        transform_kernel<true, false><<<nb, blk, 0, stream>>>(x, W1, as1, ad1, nullptr,
                                                              H, asrc, adst, NN, 128);
        gat_csr_kernel<false><<<gb, blk, 0, stream>>>(ptr, ssrc, asrc, adst, H, b1,
                                                      nullptr, nullptr, A, ET);
        transform_kernel<true, false><<<nb, blk, 0, stream>>>(A, W2, as2, ad2, nullptr,
                                                              H, asrc, adst, NN, 32);
        gat_csr_kernel<true><<<gb, blk, 0, stream>>>(ptr, ssrc, asrc, adst, H, b2,
                                                     Wr, br, out, ET);
    } else {
        // ================= tier 3: atomic path =================
        unsigned* m   = (unsigned*)ptr;
        float*    den = (float*)cnt;
        const int eb = (ET + 255) / 256;
        const int ab = (int)(((long)ET * FOUT + 255) / 256);

        hipMemsetAsync(A, 0, NF * sizeof(float), stream);
        hipMemsetAsync(m, 0, NN * sizeof(int), stream);
        hipMemsetAsync(den, 0, NN * sizeof(float), stream);
        transform_kernel<true, false><<<nb, blk, 0, stream>>>(x, W1, as1, ad1, nullptr,
                                                              H, asrc, adst, NN, 128);
        edge_max_kernel<<<eb, blk, 0, stream>>>(src, dst, asrc, adst, m, E, ET);
        edge_denom_kernel<<<eb, blk, 0, stream>>>(src, dst, asrc, adst, m, den, E, ET);
        edge_accum_kernel<<<ab, blk, 0, stream>>>(src, dst, asrc, adst, m, den, H, A, E, ET);
        finalize_kernel<<<fb, blk, 0, stream>>>(A, b1, NN);

        transform_kernel<true, false><<<nb, blk, 0, stream>>>(A, W2, as2, ad2, nullptr,
                                                              H, asrc, adst, NN, 32);
        hipMemsetAsync(A, 0, NF * sizeof(float), stream);
        hipMemsetAsync(m, 0, NN * sizeof(int), stream);
        hipMemsetAsync(den, 0, NN * sizeof(float), stream);
        edge_max_kernel<<<eb, blk, 0, stream>>>(src, dst, asrc, adst, m, E, ET);
        edge_denom_kernel<<<eb, blk, 0, stream>>>(src, dst, asrc, adst, m, den, E, ET);
        edge_accum_kernel<<<ab, blk, 0, stream>>>(src, dst, asrc, adst, m, den, H, A, E, ET);
        finalize_kernel<<<fb, blk, 0, stream>>>(A, b2, NN);

        transform_kernel<false, true><<<nb, blk, 0, stream>>>(A, Wr, nullptr, nullptr, br,
                                                              out, nullptr, nullptr, NN, 32);
    }
}

// Round 8
// 329.017 us; speedup vs baseline: 4.3572x; 1.0335x over previous
//
#include <hip/hip_runtime.h>

#define NN 100000
#define NEG_SLOPE 0.2f
#define FOUT 32
#define CAP 128
#define BKT 128                       // dst-nodes per bucket
#define NBK ((NN + BKT - 1) / BKT)    // 782
#define CHUNK 8192

__device__ __forceinline__ float lrelu(float e) { return e > 0.f ? e : NEG_SLOPE * e; }

// ---------------- node transform: h = X @ W (+bias), optional attention dots ----------------
template <bool ATT, bool ADD_BIAS>
__global__ void transform_kernel(const float* __restrict__ X, const float* __restrict__ W,
                                 const float* __restrict__ att_s, const float* __restrict__ att_d,
                                 const float* __restrict__ bias,
                                 float* __restrict__ H, float* __restrict__ a_src,
                                 float* __restrict__ a_dst, int N, int Fin) {
    __shared__ float Wl[128 * FOUT];
    __shared__ float Xl[8 * 128];
    const int t = threadIdx.x;
    const int nodeBase = blockIdx.x * 8;
    const int vprW = Fin * FOUT / 4;
    for (int i = t; i < vprW; i += 256) ((float4*)Wl)[i] = ((const float4*)W)[i];
    const int vpr = Fin / 4;
    for (int i = t; i < 8 * vpr; i += 256) {
        int r = i / vpr, c = i - r * vpr;
        int n = nodeBase + r;
        ((float4*)Xl)[i] = (n < N) ? ((const float4*)X)[(size_t)n * vpr + c]
                                   : make_float4(0.f, 0.f, 0.f, 0.f);
    }
    __syncthreads();
    const int ln = t >> 5;
    const int j  = t & 31;
    const int n  = nodeBase + ln;
    float acc = 0.f;
    for (int k = 0; k < Fin; ++k)
        acc = fmaf(Xl[ln * Fin + k], Wl[k * FOUT + j], acc);
    if (ADD_BIAS) acc += bias[j];
    if (n < N) H[(size_t)n * FOUT + j] = acc;
    if (ATT) {
        float vs = acc * att_s[j];
        float vd = acc * att_d[j];
        #pragma unroll
        for (int m = 16; m >= 1; m >>= 1) {
            vs += __shfl_xor(vs, m, 32);
            vd += __shfl_xor(vd, m, 32);
        }
        if (j == 0 && n < N) { a_src[n] = vs; a_dst[n] = vd; }
    }
}

// ---------------- CSR build (tier-1: hierarchical, no per-node global atomics) -------------
__global__ __launch_bounds__(256)
void bucket_count_kernel(const int* __restrict__ dst, int E, int* __restrict__ bktcnt) {
    __shared__ int hist[NBK];
    const int tid = threadIdx.x;
    const int e0 = blockIdx.x * CHUNK;
    const int e1 = min(e0 + CHUNK, E);
    for (int t = tid; t < NBK; t += 256) hist[t] = 0;
    __syncthreads();
    for (int i = e0 + tid; i < e1; i += 256)
        atomicAdd(&hist[((unsigned)dst[i]) / BKT], 1);
    __syncthreads();
    for (int t = tid; t < NBK; t += 256) {
        int h = hist[t];
        if (h) atomicAdd(&bktcnt[t], h);
    }
}

// generic scan; optionally writes a second copy of the result (cursor init)
template <int BS>
__global__ void scan_blocks_kernel(const int* __restrict__ in, int n,
                                   int* __restrict__ out, int* __restrict__ out2,
                                   int* __restrict__ bsums) {
    int g = blockIdx.x * BS + threadIdx.x;
    int v = (g < n) ? in[g] : 0;
    int lane = threadIdx.x & 63;
    int w = threadIdx.x >> 6;
    int x = v;
    #pragma unroll
    for (int o = 1; o < 64; o <<= 1) {
        int y = __shfl_up(x, o, 64);
        if (lane >= o) x += y;
    }
    __shared__ int ws[BS / 64];
    if (lane == 63) ws[w] = x;
    __syncthreads();
    if (threadIdx.x == 0) {
        int a = 0;
        for (int k = 0; k < BS / 64; ++k) { int tv = ws[k]; ws[k] = a; a += tv; }
        if (bsums) bsums[blockIdx.x] = a;
    }
    __syncthreads();
    int ex = x - v + ws[w];
    if (g < n) {
        out[g] = ex;
        if (out2) out2[g] = ex;
    }
}

__global__ void add_offsets_kernel(int* __restrict__ out, const int* __restrict__ bsums, int n) {
    int g = blockIdx.x * 256 + threadIdx.x;
    if (g < n) out[g] += bsums[blockIdx.x];
}

__global__ void copy_kernel(const int* __restrict__ in, int* __restrict__ out, int n) {
    int i = blockIdx.x * blockDim.x + threadIdx.x;
    if (i < n) out[i] = in[i];
}

// pass 1: bin edges by dst bucket, packed (d_local<<17 | s), contiguous runs per (block,bucket)
__global__ __launch_bounds__(256)
void partition_kernel(const int* __restrict__ src, const int* __restrict__ dst, int E,
                      int* __restrict__ bcur, unsigned* __restrict__ pbuf) {
    __shared__ int hist[NBK];
    __shared__ int runbase[NBK];
    __shared__ int c2[NBK];
    const int tid = threadIdx.x;
    const int e0 = blockIdx.x * CHUNK;
    const int e1 = min(e0 + CHUNK, E);
    for (int t = tid; t < NBK; t += 256) { hist[t] = 0; c2[t] = 0; }
    __syncthreads();
    for (int i = e0 + tid; i < e1; i += 256)
        atomicAdd(&hist[((unsigned)dst[i]) / BKT], 1);
    __syncthreads();
    for (int t = tid; t < NBK; t += 256) {
        int h = hist[t];
        runbase[t] = h ? atomicAdd(&bcur[t], h) : 0;
    }
    __syncthreads();
    for (int i = e0 + tid; i < e1; i += 256) {
        int d = dst[i], s = src[i];
        int b = ((unsigned)d) / BKT;
        int ofs = atomicAdd(&c2[b], 1);
        pbuf[runbase[b] + ofs] = (((unsigned)(d & (BKT - 1))) << 17) | (unsigned)s;
    }
}

// pass 2: one block per bucket. Local per-node counts (LDS atomics) + LDS scan
// -> writes ptr AND ssrc (self-loop at slot 0); scatter confined to the bucket's
// ~17KB contiguous window (L2-merged).
__global__ __launch_bounds__(256)
void bucket_scatter_kernel(const int* __restrict__ bktbase, const unsigned* __restrict__ pbuf,
                           int E, int* __restrict__ ptr, int* __restrict__ ssrc) {
    __shared__ int lcnt[BKT];
    __shared__ int cur[BKT];
    __shared__ int wsum[4];
    const int b = blockIdx.x;
    const int tid = threadIdx.x;
    const int n0 = b * BKT;
    const int nodes = min(BKT, NN - n0);
    const int bstart = bktbase[b];
    const int bend = (b == NBK - 1) ? E : bktbase[b + 1];
    if (tid < BKT) lcnt[tid] = 0;
    __syncthreads();
    for (int i = bstart + tid; i < bend; i += 256)
        atomicAdd(&lcnt[pbuf[i] >> 17], 1);
    __syncthreads();
    // exclusive scan of (lcnt[t] + 1) across the block (self loop included)
    int v = (tid < nodes) ? (lcnt[tid] + 1) : 0;
    int lane = tid & 63, w = tid >> 6;
    int x = v;
    #pragma unroll
    for (int o = 1; o < 64; o <<= 1) {
        int y = __shfl_up(x, o, 64);
        if (lane >= o) x += y;
    }
    if (lane == 63) wsum[w] = x;
    __syncthreads();
    if (tid == 0) {
        int a = 0;
        #pragma unroll
        for (int k = 0; k < 4; ++k) { int t2 = wsum[k]; wsum[k] = a; a += t2; }
    }
    __syncthreads();
    int ex = x - v + wsum[w];
    if (tid < nodes) {
        int p = bstart + n0 + ex;       // edges before bucket + self loops before bucket + local
        ptr[n0 + tid] = p;
        ssrc[p] = n0 + tid;             // self loop at slot 0
        cur[tid] = p + 1;
    }
    __syncthreads();
    for (int i = bstart + tid; i < bend; i += 256) {
        unsigned u = pbuf[i];
        int pos = atomicAdd(&cur[u >> 17], 1);
        ssrc[pos] = (int)(u & 0x1FFFFu);
    }
}

// ---------------- tier-2 helpers ----------------
__global__ void init_one_kernel(int* __restrict__ cnt, int n) {
    int i = blockIdx.x * blockDim.x + threadIdx.x;
    if (i < n) cnt[i] = 1;
}
__global__ void hist_kernel(const int* __restrict__ dst, int E, int* __restrict__ cnt) {
    int i = blockIdx.x * blockDim.x + threadIdx.x;
    if (i < E) atomicAdd(&cnt[dst[i]], 1);
}
__global__ void scatter_kernel(const int* __restrict__ src, const int* __restrict__ dst,
                               int E, int ET, int* __restrict__ cfill, int* __restrict__ ssrc) {
    int i = blockIdx.x * blockDim.x + threadIdx.x;
    if (i >= ET) return;
    int s, d;
    if (i < E) { s = src[i]; d = dst[i]; }
    else       { s = d = i - E; }
    int pos = atomicAdd(&cfill[d], 1);
    ssrc[pos] = s;
}

// ---------------- fused per-node GAT aggregation (CSR gather) ----------------
// one 64-lane wave per node. Pass A: cache (s,e) as int2, wave-max.
// Pass B: p=exp(e-mx) overwrites e, wave-sum. Pass C: eighth-wave float4 gathers,
// 2-unrolled (16 H-rows in flight/wave); inv applied once after reduction.
// __syncthreads() between passes: pass C reads OTHER lanes' LDS writes — a
// compiler-level fence is required (round-7 lesson: barrier-free version raced).
template <bool FUSE_OUT>
__global__ __launch_bounds__(256)
void gat_csr_kernel(const int* __restrict__ ptr, const int* __restrict__ ssrc,
                    const float* __restrict__ asrc, const float* __restrict__ adst,
                    const float* __restrict__ H, const float* __restrict__ bias,
                    const float* __restrict__ Wr, const float* __restrict__ br,
                    float* __restrict__ out, int ET) {
    __shared__ float Wl[32 * 32];
    __shared__ int2  seb[4][CAP];
    __shared__ float hbuf[4][FOUT];
    const int tid = threadIdx.x;
    if (FUSE_OUT) {
        for (int i = tid; i < 1024; i += 256) Wl[i] = Wr[i];
    }
    const int w = tid >> 6, lane = tid & 63;
    const int wid = blockIdx.x * 4 + w;
    const int beg = ptr[wid];
    const int end = (wid == NN - 1) ? ET : ptr[wid + 1];
    const int deg = end - beg;
    const int cap = min(deg, CAP);
    const float ad = adst[wid];

    // pass A: gather asrc once, cache (s, e), track max
    float mx = -1e30f;
    for (int k = lane; k < cap; k += 64) {
        int s = ssrc[beg + k];
        float e = lrelu(asrc[s] + ad);
        seb[w][k] = make_int2(s, __float_as_int(e));
        mx = fmaxf(mx, e);
    }
    for (int k = cap + lane; k < deg; k += 64) {
        int s = ssrc[beg + k];
        mx = fmaxf(mx, lrelu(asrc[s] + ad));
    }
    #pragma unroll
    for (int o = 32; o; o >>= 1) mx = fmaxf(mx, __shfl_xor(mx, o, 64));
    __syncthreads();                 // seb (s,e) visible across lanes

    // pass B: p = exp(e - mx), overwrite e slot, wave-sum
    float sm = 0.f;
    for (int k = lane; k < cap; k += 64) {
        float p = __expf(__int_as_float(seb[w][k].y) - mx);
        seb[w][k].y = __float_as_int(p);
        sm += p;
    }
    for (int k = cap + lane; k < deg; k += 64) {
        int s = ssrc[beg + k];
        sm += __expf(lrelu(asrc[s] + ad) - mx);
    }
    #pragma unroll
    for (int o = 32; o; o >>= 1) sm += __shfl_xor(sm, o, 64);
    const float inv = 1.f / (sm + 1e-16f);
    __syncthreads();                 // seb p-values (and Wl) visible

    // pass C: eighth o handles edges k === o (mod 8); lane t holds features 4t..4t+3
    const int o = lane >> 3, t = lane & 7;
    float4 a0 = make_float4(0.f, 0.f, 0.f, 0.f);
    float4 a1 = make_float4(0.f, 0.f, 0.f, 0.f);
    int k = o;
    for (; k + 8 < deg; k += 16) {
        int s0; float p0;
        if (k < cap) { int2 v = seb[w][k]; s0 = v.x; p0 = __int_as_float(v.y); }
        else { s0 = ssrc[beg + k]; p0 = __expf(lrelu(asrc[s0] + ad) - mx); }
        int k1 = k + 8; int s1; float p1;
        if (k1 < cap) { int2 v = seb[w][k1]; s1 = v.x; p1 = __int_as_float(v.y); }
        else { s1 = ssrc[beg + k1]; p1 = __expf(lrelu(asrc[s1] + ad) - mx); }
        float4 h0 = *(const float4*)(H + (size_t)s0 * FOUT + 4 * t);
        float4 h1 = *(const float4*)(H + (size_t)s1 * FOUT + 4 * t);
        a0.x = fmaf(p0, h0.x, a0.x); a0.y = fmaf(p0, h0.y, a0.y);
        a0.z = fmaf(p0, h0.z, a0.z); a0.w = fmaf(p0, h0.w, a0.w);
        a1.x = fmaf(p1, h1.x, a1.x); a1.y = fmaf(p1, h1.y, a1.y);
        a1.z = fmaf(p1, h1.z, a1.z); a1.w = fmaf(p1, h1.w, a1.w);
    }
    for (; k < deg; k += 8) {
        int s; float p;
        if (k < cap) { int2 v = seb[w][k]; s = v.x; p = __int_as_float(v.y); }
        else { s = ssrc[beg + k]; p = __expf(lrelu(asrc[s] + ad) - mx); }
        float4 h = *(const float4*)(H + (size_t)s * FOUT + 4 * t);
        a0.x = fmaf(p, h.x, a0.x); a0.y = fmaf(p, h.y, a0.y);
        a0.z = fmaf(p, h.z, a0.z); a0.w = fmaf(p, h.w, a0.w);
    }
    float4 a = make_float4(a0.x + a1.x, a0.y + a1.y, a0.z + a1.z, a0.w + a1.w);
    #pragma unroll
    for (int off = 8; off <= 32; off <<= 1) {
        a.x += __shfl_xor(a.x, off, 64);
        a.y += __shfl_xor(a.y, off, 64);
        a.z += __shfl_xor(a.z, off, 64);
        a.w += __shfl_xor(a.w, off, 64);
    }

    if (!FUSE_OUT) {
        if (lane < 8) {
            float4 bv = *(const float4*)(bias + 4 * t);
            float4 v;
            v.x = fmaxf(fmaf(a.x, inv, bv.x), 0.f);
            v.y = fmaxf(fmaf(a.y, inv, bv.y), 0.f);
            v.z = fmaxf(fmaf(a.z, inv, bv.z), 0.f);
            v.w = fmaxf(fmaf(a.w, inv, bv.w), 0.f);
            *(float4*)(out + (size_t)wid * FOUT + 4 * t) = v;
        }
    } else {
        if (lane < 8) {
            float4 bv = *(const float4*)(bias + 4 * t);
            hbuf[w][4 * t]     = fmaxf(fmaf(a.x, inv, bv.x), 0.f);
            hbuf[w][4 * t + 1] = fmaxf(fmaf(a.y, inv, bv.y), 0.f);
            hbuf[w][4 * t + 2] = fmaxf(fmaf(a.z, inv, bv.z), 0.f);
            hbuf[w][4 * t + 3] = fmaxf(fmaf(a.w, inv, bv.w), 0.f);
        }
        __syncthreads();             // hbuf visible (uniform barrier)
        if (lane < 8) {
            float4 r = *(const float4*)(br + 4 * t);
            const float4* W4 = (const float4*)Wl;
            #pragma unroll
            for (int j = 0; j < 32; ++j) {
                float hj = hbuf[w][j];
                float4 wv = W4[j * 8 + t];
                r.x = fmaf(hj, wv.x, r.x); r.y = fmaf(hj, wv.y, r.y);
                r.z = fmaf(hj, wv.z, r.z); r.w = fmaf(hj, wv.w, r.w);
            }
            *(float4*)(out + (size_t)wid * FOUT + 4 * t) = r;
        }
    }
}

// ---------------- tier-3 fallback (round-2 proven atomic path) ----------------
__device__ __forceinline__ unsigned ordf(float f) {
    unsigned u = __float_as_uint(f);
    return (u & 0x80000000u) ? ~u : (u | 0x80000000u);
}
__device__ __forceinline__ float unordf(unsigned u) {
    return (u & 0x80000000u) ? __uint_as_float(u & 0x7FFFFFFFu) : __uint_as_float(~u);
}
__device__ __forceinline__ void edge_sd(int i, int E, const int* __restrict__ src,
                                        const int* __restrict__ dst, int& s, int& d) {
    if (i < E) { s = src[i]; d = dst[i]; }
    else       { s = d = i - E; }
}
__global__ void edge_max_kernel(const int* __restrict__ src, const int* __restrict__ dst,
                                const float* __restrict__ a_src, const float* __restrict__ a_dst,
                                unsigned* __restrict__ m, int E, int ET) {
    int i = blockIdx.x * blockDim.x + threadIdx.x;
    if (i >= ET) return;
    int s, d; edge_sd(i, E, src, dst, s, d);
    atomicMax(m + d, ordf(lrelu(a_src[s] + a_dst[d])));
}
__global__ void edge_denom_kernel(const int* __restrict__ src, const int* __restrict__ dst,
                                  const float* __restrict__ a_src, const float* __restrict__ a_dst,
                                  const unsigned* __restrict__ m, float* __restrict__ denom,
                                  int E, int ET) {
    int i = blockIdx.x * blockDim.x + threadIdx.x;
    if (i >= ET) return;
    int s, d; edge_sd(i, E, src, dst, s, d);
    atomicAdd(denom + d, __expf(lrelu(a_src[s] + a_dst[d]) - unordf(m[d])));
}
__global__ void edge_accum_kernel(const int* __restrict__ src, const int* __restrict__ dst,
                                  const float* __restrict__ a_src, const float* __restrict__ a_dst,
                                  const unsigned* __restrict__ m, const float* __restrict__ denom,
                                  const float* __restrict__ H, float* __restrict__ accum,
                                  int E, int ET) {
    long tid = (long)blockIdx.x * blockDim.x + threadIdx.x;
    if (tid >= (long)ET * FOUT) return;
    int i = (int)(tid >> 5);
    int j = (int)(tid & 31);
    int s, d; edge_sd(i, E, src, dst, s, d);
    float w = __expf(lrelu(a_src[s] + a_dst[d]) - unordf(m[d])) / (denom[d] + 1e-16f);
    atomicAdd(accum + (long)d * FOUT + j, w * H[(long)s * FOUT + j]);
}
__global__ void finalize_kernel(float* __restrict__ accum, const float* __restrict__ bias, int N) {
    int tid = blockIdx.x * blockDim.x + threadIdx.x;
    if (tid >= N * FOUT) return;
    int j = tid & 31;
    accum[tid] = fmaxf(accum[tid] + bias[j], 0.f);
}

extern "C" void kernel_launch(void* const* d_in, const int* in_sizes, int n_in,
                              void* d_out, int out_size, void* d_ws, size_t ws_size,
                              hipStream_t stream) {
    const float* x   = (const float*)d_in[0];
    const int*   ei  = (const int*)d_in[1];
    const float* W1  = (const float*)d_in[2];
    const float* as1 = (const float*)d_in[3];
    const float* ad1 = (const float*)d_in[4];
    const float* b1  = (const float*)d_in[5];
    const float* W2  = (const float*)d_in[6];
    const float* as2 = (const float*)d_in[7];
    const float* ad2 = (const float*)d_in[8];
    const float* b2  = (const float*)d_in[9];
    const float* Wr  = (const float*)d_in[10];
    const float* br  = (const float*)d_in[11];
    float* out = (float*)d_out;

    const int E  = in_sizes[1] / 2;
    const int*  src = ei;
    const int*  dst = ei + E;
    const int ET = E + NN;

    const size_t NF = (size_t)NN * FOUT;
    // layout: A(NF) | H(NF) | asrc(NN) | adst(NN) | ptr(NN) | cnt(NN) | bsum(512) | ssrc(ET)
    float* A     = (float*)d_ws;
    float* H     = A + NF;
    float* asrc  = H + NF;
    float* adst  = asrc + NN;
    int*   ptr   = (int*)(adst + NN);
    int*   cnt   = ptr + NN;
    int*   bsum  = cnt + NN;
    int*   ssrc  = bsum + 512;
    const size_t need = (2 * NF + 4 * (size_t)NN + 512 + (size_t)ET) * 4;

    dim3 blk(256);
    const int nb  = (NN + 7) / 8;
    const int fb  = (NN * FOUT + 255) / 256;
    const int nb1 = (NN + 255) / 256;   // 391

    if (ws_size >= need && (size_t)E <= NF) {
        // ================= tier 1: hierarchical CSR, no per-node global atomics ==========
        unsigned* pbuf    = (unsigned*)A;       // E entries (A dead during CSR build)
        int*      bktcnt  = cnt;                // NBK
        int*      bktbase = cnt + 1024;         // NBK
        int*      bcur    = cnt + 2048;         // NBK
        const int cb = (E + CHUNK - 1) / CHUNK;
        const int gb = NN / 4;

        hipMemsetAsync(bktcnt, 0, NBK * sizeof(int), stream);
        bucket_count_kernel<<<cb, blk, 0, stream>>>(dst, E, bktcnt);
        scan_blocks_kernel<1024><<<1, 1024, 0, stream>>>(bktcnt, NBK, bktbase, bcur, nullptr);
        partition_kernel<<<cb, blk, 0, stream>>>(src, dst, E, bcur, pbuf);
        bucket_scatter_kernel<<<NBK, blk, 0, stream>>>(bktbase, pbuf, E, ptr, ssrc);

        // layer 1
        transform_kernel<true, false><<<nb, blk, 0, stream>>>(x, W1, as1, ad1, nullptr,
                                                              H, asrc, adst, NN, 128);
        gat_csr_kernel<false><<<gb, blk, 0, stream>>>(ptr, ssrc, asrc, adst, H, b1,
                                                      nullptr, nullptr, A, ET);
        // layer 2 + fused readout
        transform_kernel<true, false><<<nb, blk, 0, stream>>>(A, W2, as2, ad2, nullptr,
                                                              H, asrc, adst, NN, 32);
        gat_csr_kernel<true><<<gb, blk, 0, stream>>>(ptr, ssrc, asrc, adst, H, b2,
                                                     Wr, br, out, ET);
    } else if (ws_size >= need) {
        // ================= tier 2: per-node hist + simple scatter =================
        const int gb = NN / 4;
        init_one_kernel<<<nb1, blk, 0, stream>>>(cnt, NN);
        hist_kernel<<<(E + 255) / 256, blk, 0, stream>>>(dst, E, cnt);
        scan_blocks_kernel<256><<<nb1, blk, 0, stream>>>(cnt, NN, ptr, nullptr, bsum);
        scan_blocks_kernel<512><<<1, 512, 0, stream>>>(bsum, nb1, bsum, nullptr, nullptr);
        add_offsets_kernel<<<nb1, blk, 0, stream>>>(ptr, bsum, NN);
        copy_kernel<<<nb1, blk, 0, stream>>>(ptr, cnt, NN);
        scatter_kernel<<<(ET + 255) / 256, blk, 0, stream>>>(src, dst, E, ET, cnt, ssrc);

        transform_kernel<true, false><<<nb, blk, 0, stream>>>(x, W1, as1, ad1, nullptr,
                                                              H, asrc, adst, NN, 128);
        gat_csr_kernel<false><<<gb, blk, 0, stream>>>(ptr, ssrc, asrc, adst, H, b1,
                                                      nullptr, nullptr, A, ET);
        transform_kernel<true, false><<<nb, blk, 0, stream>>>(A, W2, as2, ad2, nullptr,
                                                              H, asrc, adst, NN, 32);
        gat_csr_kernel<true><<<gb, blk, 0, stream>>>(ptr, ssrc, asrc, adst, H, b2,
                                                     Wr, br, out, ET);
    } else {
        // ================= tier 3: atomic path =================
        unsigned* m   = (unsigned*)ptr;
        float*    den = (float*)cnt;
        const int eb = (ET + 255) / 256;
        const int ab = (int)(((long)ET * FOUT + 255) / 256);

        hipMemsetAsync(A, 0, NF * sizeof(float), stream);
        hipMemsetAsync(m, 0, NN * sizeof(int), stream);
        hipMemsetAsync(den, 0, NN * sizeof(float), stream);
        transform_kernel<true, false><<<nb, blk, 0, stream>>>(x, W1, as1, ad1, nullptr,
                                                              H, asrc, adst, NN, 128);
        edge_max_kernel<<<eb, blk, 0, stream>>>(src, dst, asrc, adst, m, E, ET);
        edge_denom_kernel<<<eb, blk, 0, stream>>>(src, dst, asrc, adst, m, den, E, ET);
        edge_accum_kernel<<<ab, blk, 0, stream>>>(src, dst, asrc, adst, m, den, H, A, E, ET);
        finalize_kernel<<<fb, blk, 0, stream>>>(A, b1, NN);

        transform_kernel<true, false><<<nb, blk, 0, stream>>>(A, W2, as2, ad2, nullptr,
                                                              H, asrc, adst, NN, 32);
        hipMemsetAsync(A, 0, NF * sizeof(float), stream);
        hipMemsetAsync(m, 0, NN * sizeof(int), stream);
        hipMemsetAsync(den, 0, NN * sizeof(float), stream);
        edge_max_kernel<<<eb, blk, 0, stream>>>(src, dst, asrc, adst, m, E, ET);
        edge_denom_kernel<<<eb, blk, 0, stream>>>(src, dst, asrc, adst, m, den, E, ET);
        edge_accum_kernel<<<ab, blk, 0, stream>>>(src, dst, asrc, adst, m, den, H, A, E, ET);
        finalize_kernel<<<fb, blk, 0, stream>>>(A, b2, NN);

        transform_kernel<false, true><<<nb, blk, 0, stream>>>(A, Wr, nullptr, nullptr, br,
                                                              out, nullptr, nullptr, NN, 32);
    }
}